// Round 1
// 3383.802 us; speedup vs baseline: 1.0484x; 1.0484x over previous
//
#include <hip/hip_runtime.h>
#include <hip/hip_bf16.h>

#define LYR  6
#define BATCH 2
#define TOK  64
#define SEQ  1024
#define EMB  768
#define HEADS 12
#define HDK  64
#define DFF  3072

typedef __bf16 bf16_t;
typedef __bf16 bf16x8 __attribute__((ext_vector_type(8)));
typedef float  f32x4  __attribute__((ext_vector_type(4)));

static __device__ __forceinline__ unsigned short bfbits(float f) {
    bf16_t b = (bf16_t)f; return *(unsigned short*)&b;
}
static __device__ __forceinline__ float loadf(const void* p, size_t e, int f32) {
    if (f32) return ((const float*)p)[e];
    return (float)((const bf16_t*)p)[e];
}
static __device__ __forceinline__ ushort4 load4bf(const void* p, size_t e, int f32) {
    if (f32) {
        float4 f = *(const float4*)((const float*)p + e);
        ushort4 u; u.x = bfbits(f.x); u.y = bfbits(f.y); u.z = bfbits(f.z); u.w = bfbits(f.w);
        return u;
    }
    return *(const ushort4*)((const unsigned short*)p + e);
}

// ---------------------------------------------------------------------------
// dtype detector: scan first 4096 16-bit chunks of Wq as bf16.
// ---------------------------------------------------------------------------
__global__ __launch_bounds__(256)
void detect_k(const void* w, int* flag)
{
    __shared__ int bad;
    if (threadIdx.x == 0) bad = 0;
    __syncthreads();
    const unsigned short* p = (const unsigned short*)w;
    int local = 0;
    for (int i = threadIdx.x; i < 4096; i += 256) {
        float v = (float)(*(const bf16_t*)&p[i]);
        if (!(v < 1e3f && v > -1e3f)) local = 1;   // catches NaN too
    }
    if (local) atomicOr(&bad, 1);
    __syncthreads();
    if (threadIdx.x == 0) *flag = bad;
}

// ---------------------------------------------------------------------------
// Generic 64x64-tile MFMA GEMM.  C = A * B (fp32 accumulate), bf16 MFMA.
// EPI: 0 = bf16 store, 1 = bf16 relu, 2 = fp32
// ---------------------------------------------------------------------------
template<int EPI, bool BTRANS, bool AF32>
__global__ __launch_bounds__(256)
void gemm_k(const void* __restrict__ Aall, long lda, long sAb, long sAh,
            const void* __restrict__ Ball, long ldb, long boff0, long sBb, long sBh,
            void* __restrict__ Call, long ldc, long sCb, long sCh,
            int K, float scale, const int* __restrict__ pad,
            const int* __restrict__ bf32p)
{
    __shared__ __align__(16) unsigned short As[64][40];
    __shared__ __align__(16) unsigned short Bs[64][40];   // stored [n][k]

    const int bF32 = bf32p ? *bf32p : 0;
    const int z  = blockIdx.z;
    const int bq = z / HEADS, hq = z % HEADS;
    const size_t aoff = (size_t)bq * sAb + (size_t)hq * sAh;
    const size_t boff = (size_t)boff0 + (size_t)bq * sBb + (size_t)hq * sBh;
    const size_t coff = (size_t)bq * sCb + (size_t)hq * sCh;

    const int tid  = threadIdx.x;
    const int lane = tid & 63;
    const int wave = tid >> 6;
    const int bm = blockIdx.x * 64;
    const int bn = blockIdx.y * 64;

    f32x4 acc[4];
#pragma unroll
    for (int t = 0; t < 4; t++) acc[t] = (f32x4){0.f, 0.f, 0.f, 0.f};

    for (int k0 = 0; k0 < K; k0 += 32) {
#pragma unroll
        for (int i = 0; i < 2; i++) {
            int e = (tid + i * 256) * 4;
            int r = e >> 5, c = e & 31;
            ushort4 u = load4bf(Aall, aoff + (size_t)(bm + r) * lda + k0 + c, AF32 ? 1 : 0);
            *(ushort4*)&As[r][c] = u;
        }
        if (BTRANS) {
#pragma unroll
            for (int i = 0; i < 2; i++) {
                int e = (tid + i * 256) * 4;
                int r = e >> 5, c = e & 31;
                ushort4 u = load4bf(Ball, boff + (size_t)(bn + r) * ldb + k0 + c, bF32);
                *(ushort4*)&Bs[r][c] = u;
            }
        } else {
#pragma unroll
            for (int i = 0; i < 2; i++) {
                int e = (tid + i * 256) * 4;
                int kk = e >> 6, n = e & 63;
                ushort4 u = load4bf(Ball, boff + (size_t)(k0 + kk) * ldb + bn + n, bF32);
                Bs[n + 0][kk] = u.x; Bs[n + 1][kk] = u.y;
                Bs[n + 2][kk] = u.z; Bs[n + 3][kk] = u.w;
            }
        }
        __syncthreads();

        const int mrow = wave * 16 + (lane & 15);
        const int kq   = (lane >> 4) * 8;
        bf16x8 av = *(const bf16x8*)&As[mrow][kq];
#pragma unroll
        for (int t = 0; t < 4; t++) {
            bf16x8 bv = *(const bf16x8*)&Bs[t * 16 + (lane & 15)][kq];
            acc[t] = __builtin_amdgcn_mfma_f32_16x16x32_bf16(av, bv, acc[t], 0, 0, 0);
        }
        __syncthreads();
    }

    const int colb = bn + (lane & 15);
    const int rowb = bm + wave * 16 + ((lane >> 4) << 2);
#pragma unroll
    for (int t = 0; t < 4; t++) {
        const int col = colb + t * 16;
#pragma unroll
        for (int r = 0; r < 4; r++) {
            const int row = rowb + r;
            float v = acc[t][r];
            size_t idx = coff + (size_t)row * ldc + col;
            if constexpr (EPI == 0) {
                ((bf16_t*)Call)[idx] = (bf16_t)v;
            } else if constexpr (EPI == 1) {
                ((bf16_t*)Call)[idx] = (bf16_t)(v > 0.f ? v : 0.f);
            } else {
                ((float*)Call)[idx] = v;
            }
        }
    }
}

__global__ __launch_bounds__(256)
void posadd_k(const void* __restrict__ x, const void* __restrict__ tp,
              const void* __restrict__ sp, float* __restrict__ X,
              bf16_t* __restrict__ XB, int* __restrict__ pad,
              const int* __restrict__ flagp)
{
    const int f32 = *flagp;
    const int row = blockIdx.x;              // b*S + s
    const int s = row % SEQ;
    const int f = s / TOK, tt = s % TOK;
    const int tid = threadIdx.x;
#pragma unroll
    for (int i = 0; i < 3; i++) {
        int e = tid + i * 256;
        float v = loadf(x, (size_t)row * EMB + e, f32)
                + loadf(tp, (size_t)f * EMB + e, f32)
                + loadf(sp, (size_t)tt * EMB + e, f32);
        X[(size_t)row * EMB + e]  = v;
        XB[(size_t)row * EMB + e] = (bf16_t)v;
        if (e == 0) pad[row] = (v == 0.0f) ? 1 : 0;
    }
}

// ---------------------------------------------------------------------------
// Fused attention: scores (bf16 MFMA, fp32 acc, in registers) -> softmax
// (in-register + cross-wave LDS reduce) -> probs to d_out + LDS (bf16)
// -> PV (bf16 MFMA) -> ctx.  One block = 16 query rows of one (b,h).
// Causal: only nt = bx/4+1 col tiles computed; tail written as exact zeros
// (matches fp32 exp underflow in the reference).
// ---------------------------------------------------------------------------
__global__ __launch_bounds__(256)
void attn_k(const bf16_t* __restrict__ Q, const bf16_t* __restrict__ K,
            const bf16_t* __restrict__ V, bf16_t* __restrict__ CTX,
            void* __restrict__ outp, long probs_off,
            const int* __restrict__ pad, const int* __restrict__ flagp)
{
    __shared__ __align__(16) unsigned short KV[64][72];   // K tile, then V^T tile
    __shared__ __align__(16) unsigned short P[16][1032];  // probs bf16 [row][col]
    __shared__ float redm[4][16];
    __shared__ float reds[4][16];

    const int f32 = *flagp;
    const int bx  = blockIdx.x;              // query tile (16 rows)
    const int z   = blockIdx.y;              // b*H + h
    const int bq  = z / HEADS, h = z % HEADS;
    const int tid = threadIdx.x;
    const int lane = tid & 63;
    const int w    = tid >> 6;
    const int l15  = lane & 15;
    const int l4   = lane >> 4;

    const size_t xoff = (size_t)bq * SEQ * EMB + (size_t)h * HDK;
    const int row0 = bx * 16;
    const int nt   = (bx >> 2) + 1;          // causal col-tile count (of 16)

    // Q fragments (A operand): rows row0+l15, k = ks*32 + l4*8
    bf16x8 aq0, aq1;
    {
        const bf16_t* qp = Q + xoff + (size_t)(row0 + l15) * EMB + l4 * 8;
        aq0 = *(const bf16x8*)qp;
        aq1 = *(const bf16x8*)(qp + 32);
    }

    f32x4 sc[16];   // scores: wave w owns cols ct*64 + w*16 + l15, rows l4*4+r

    // ---- QK^T -------------------------------------------------------------
#pragma unroll
    for (int ct = 0; ct < 16; ct++) {
        if (ct < nt) {
            {
                const int tk = tid >> 3, d0 = (tid & 7) * 8;
                const bf16_t* kp = K + xoff + (size_t)(ct * 64 + tk) * EMB + d0;
                *(uint4*)&KV[tk][d0]      = *(const uint4*)kp;
                *(uint4*)&KV[tk + 32][d0] = *(const uint4*)(kp + (size_t)32 * EMB);
            }
            __syncthreads();
            bf16x8 b0 = *(const bf16x8*)&KV[w * 16 + l15][l4 * 8];
            bf16x8 b1 = *(const bf16x8*)&KV[w * 16 + l15][32 + l4 * 8];
            f32x4 a = (f32x4){0.f, 0.f, 0.f, 0.f};
            a = __builtin_amdgcn_mfma_f32_16x16x32_bf16(aq0, b0, a, 0, 0, 0);
            a = __builtin_amdgcn_mfma_f32_16x16x32_bf16(aq1, b1, a, 0, 0, 0);
            const int col = ct * 64 + w * 16 + l15;
            const int pd  = pad[bq * SEQ + col];
#pragma unroll
            for (int r = 0; r < 4; r++) {
                float v = a[r] * 0.125f;
                if (col > row0 + l4 * 4 + r || pd) v = -1e9f;
                sc[ct][r] = v;
            }
            __syncthreads();
        }
    }

    // ---- softmax ----------------------------------------------------------
    float m4[4], s4[4];
#pragma unroll
    for (int r = 0; r < 4; r++) m4[r] = -3.0e38f;
#pragma unroll
    for (int ct = 0; ct < 16; ct++)
        if (ct < nt) {
#pragma unroll
            for (int r = 0; r < 4; r++) m4[r] = fmaxf(m4[r], sc[ct][r]);
        }
#pragma unroll
    for (int r = 0; r < 4; r++) {
        m4[r] = fmaxf(m4[r], __shfl_xor(m4[r], 1, 64));
        m4[r] = fmaxf(m4[r], __shfl_xor(m4[r], 2, 64));
        m4[r] = fmaxf(m4[r], __shfl_xor(m4[r], 4, 64));
        m4[r] = fmaxf(m4[r], __shfl_xor(m4[r], 8, 64));
    }
    if (l15 == 0) {
#pragma unroll
        for (int r = 0; r < 4; r++) redm[w][l4 * 4 + r] = m4[r];
    }
    __syncthreads();
#pragma unroll
    for (int r = 0; r < 4; r++) {
        const int row = l4 * 4 + r;
        m4[r] = fmaxf(fmaxf(redm[0][row], redm[1][row]),
                      fmaxf(redm[2][row], redm[3][row]));
        s4[r] = 0.f;
    }
#pragma unroll
    for (int ct = 0; ct < 16; ct++)
        if (ct < nt) {
#pragma unroll
            for (int r = 0; r < 4; r++) {
                float e = __expf(sc[ct][r] - m4[r]);
                sc[ct][r] = e;
                s4[r] += e;
            }
        }
#pragma unroll
    for (int r = 0; r < 4; r++) {
        s4[r] += __shfl_xor(s4[r], 1, 64);
        s4[r] += __shfl_xor(s4[r], 2, 64);
        s4[r] += __shfl_xor(s4[r], 4, 64);
        s4[r] += __shfl_xor(s4[r], 8, 64);
    }
    if (l15 == 0) {
#pragma unroll
        for (int r = 0; r < 4; r++) reds[w][l4 * 4 + r] = s4[r];
    }
    __syncthreads();
    float inv[4];
#pragma unroll
    for (int r = 0; r < 4; r++) {
        const int row = l4 * 4 + r;
        inv[r] = 1.0f / (reds[0][row] + reds[1][row] + reds[2][row] + reds[3][row]);
    }

    // ---- write probs: d_out (dtype-branched) + P_lds (bf16 for PV) --------
    const size_t obase = (size_t)probs_off + ((size_t)z * SEQ + row0) * SEQ;
#pragma unroll
    for (int ct = 0; ct < 16; ct++) {
        if (ct < nt) {
            const int col = ct * 64 + w * 16 + l15;
#pragma unroll
            for (int r = 0; r < 4; r++) {
                const int row = l4 * 4 + r;
                const float p  = sc[ct][r] * inv[r];
                const float p2 = __shfl_xor(p, 1, 64);   // col-neighbor value
                if (!(lane & 1)) {
                    const unsigned int pk =
                        ((unsigned int)bfbits(p2) << 16) | bfbits(p);
                    *(unsigned int*)&P[row][col] = pk;   // col even here
                    if (!f32)
                        *(unsigned int*)((unsigned short*)outp + obase +
                                         (size_t)row * SEQ + col) = pk;
                }
                if (f32)
                    ((float*)outp)[obase + (size_t)row * SEQ + col] = p;
            }
        }
    }
    // causal tail: exact zeros
    {
        const int c0 = nt * 64;
        if (c0 < SEQ) {
            const int rr = tid >> 4, ii = tid & 15;
            if (f32) {
                float* op = (float*)outp + obase + (size_t)rr * SEQ;
                const float4 zz = {0.f, 0.f, 0.f, 0.f};
                for (int c = c0 + ii * 4; c < SEQ; c += 64) *(float4*)(op + c) = zz;
            } else {
                unsigned short* op = (unsigned short*)outp + obase + (size_t)rr * SEQ;
                const uint4 zz = {0u, 0u, 0u, 0u};
                for (int c = c0 + ii * 8; c < SEQ; c += 128) *(uint4*)(op + c) = zz;
            }
        }
    }

    // ---- PV ---------------------------------------------------------------
    f32x4 co = (f32x4){0.f, 0.f, 0.f, 0.f};
#pragma unroll
    for (int kt = 0; kt < 16; kt++) {
        if (kt < nt) {
            __syncthreads();       // KV reads from prev tile done; P writes done
#pragma unroll
            for (int i = 0; i < 4; i++) {
                const int e = (tid + i * 256) * 4;
                const int kk = e >> 6, n = e & 63;
                const ushort4 u = *(const ushort4*)
                    ((const unsigned short*)V + xoff + (size_t)(kt * 64 + kk) * EMB + n);
                KV[n + 0][kk] = u.x; KV[n + 1][kk] = u.y;
                KV[n + 2][kk] = u.z; KV[n + 3][kk] = u.w;
            }
            __syncthreads();
            bf16x8 a0 = *(const bf16x8*)&P[l15][kt * 64 + l4 * 8];
            bf16x8 a1 = *(const bf16x8*)&P[l15][kt * 64 + 32 + l4 * 8];
            bf16x8 b0 = *(const bf16x8*)&KV[w * 16 + l15][l4 * 8];
            bf16x8 b1 = *(const bf16x8*)&KV[w * 16 + l15][32 + l4 * 8];
            co = __builtin_amdgcn_mfma_f32_16x16x32_bf16(a0, b0, co, 0, 0, 0);
            co = __builtin_amdgcn_mfma_f32_16x16x32_bf16(a1, b1, co, 0, 0, 0);
        }
    }
    bf16_t* cp = CTX + xoff + (size_t)row0 * EMB + w * 16 + l15;
#pragma unroll
    for (int r = 0; r < 4; r++)
        cp[(size_t)(l4 * 4 + r) * EMB] = (bf16_t)co[r];
}

static __device__ __forceinline__ float bsum(float v, float* red)
{
#pragma unroll
    for (int off = 32; off; off >>= 1) v += __shfl_down(v, off, 64);
    const int lane = threadIdx.x & 63, w = threadIdx.x >> 6;
    __syncthreads();
    if (lane == 0) red[w] = v;
    __syncthreads();
    return red[0] + red[1] + red[2] + red[3];
}

__global__ __launch_bounds__(256)
void ln_k(const float* __restrict__ proj, float* __restrict__ X,
          bf16_t* __restrict__ XB, const void* __restrict__ g, long goff,
          const void* __restrict__ bb, long boff2, const int* __restrict__ flagp)
{
    const int f32 = *flagp;
    const int row = blockIdx.x;
    const float* p = proj + (size_t)row * EMB;
    float* x  = X  + (size_t)row * EMB;
    bf16_t* xb = XB + (size_t)row * EMB;
    const int tid = threadIdx.x;
    __shared__ float red[4];

    float v[3];
    float sum = 0.f;
#pragma unroll
    for (int i = 0; i < 3; i++) { int e = tid + i * 256; v[i] = p[e] + x[e]; sum += v[i]; }
    sum = bsum(sum, red);
    const float mean = sum * (1.0f / EMB);

    float vs = 0.f;
#pragma unroll
    for (int i = 0; i < 3; i++) { float d = v[i] - mean; vs += d * d; }
    vs = bsum(vs, red);
    const float rstd = rsqrtf(vs * (1.0f / EMB) + 1e-5f);

#pragma unroll
    for (int i = 0; i < 3; i++) {
        int e = tid + i * 256;
        float y = (v[i] - mean) * rstd * loadf(g, goff + e, f32) + loadf(bb, boff2 + e, f32);
        x[e] = y;
        xb[e] = (bf16_t)y;
    }
}

__global__ __launch_bounds__(256)
void copyout_k(const float* __restrict__ X, void* __restrict__ outp,
               const int* __restrict__ flagp)
{
    const int f32 = *flagp;
    int i = blockIdx.x * 256 + threadIdx.x;
    float v = X[i];
    if (f32) ((float*)outp)[i] = v;
    else     ((bf16_t*)outp)[i] = (bf16_t)v;
}

// ---------------------------------------------------------------------------
extern "C" void kernel_launch(void* const* d_in, const int* in_sizes, int n_in,
                              void* d_out, int out_size, void* d_ws, size_t ws_size,
                              hipStream_t stream)
{
    const void* x  = d_in[0];
    const void* tp = d_in[1];
    const void* sp = d_in[2];
    const void* Wq = d_in[3];
    const void* Wk = d_in[4];
    const void* Wv = d_in[5];
    const void* Wo = d_in[6];
    const void* g1 = d_in[7];
    const void* b1 = d_in[8];
    const void* W1 = d_in[9];
    const void* W2 = d_in[10];
    const void* g2 = d_in[11];
    const void* b2 = d_in[12];

    const size_t BS   = (size_t)BATCH * SEQ;                 // 2048
    const size_t BSE  = BS * EMB;                             // 1.57M
    const size_t ATT1 = (size_t)BATCH * HEADS * SEQ * SEQ;    // 25.2M / layer

    char* ws = (char*)d_ws;
    size_t off = 0;
    auto alloc = [&](size_t bytes) { void* p = ws + off; off += (bytes + 255) & ~255ULL; return p; };

    float*  X    = (float*)alloc(BSE * 4);
    bf16_t* XB   = (bf16_t*)alloc(BSE * 2);
    bf16_t* QB   = (bf16_t*)alloc(BSE * 2);
    bf16_t* KB   = (bf16_t*)alloc(BSE * 2);
    bf16_t* VB   = (bf16_t*)alloc(BSE * 2);
    bf16_t* CTXB = (bf16_t*)alloc(BSE * 2);
    bf16_t* HB   = (bf16_t*)alloc(BS * DFF * 2);
    float*  PRJ  = (float*)alloc(BSE * 4);
    int*    pad  = (int*)alloc(BS * 4);
    int*    flag = (int*)alloc(256);

    detect_k<<<dim3(1), 256, 0, stream>>>(Wq, flag);
    posadd_k<<<dim3((int)BS), 256, 0, stream>>>(x, tp, sp, X, XB, pad, flag);

    for (int l = 0; l < LYR; l++) {
        const long oW  = (long)l * EMB * EMB;
        const long oF1 = (long)l * EMB * DFF;
        const long oF2 = (long)l * DFF * EMB;
        const long oLN = (long)l * EMB;
        const long probs_off = (long)(BSE + (size_t)l * ATT1);

        // QKV projections: [2048,768] x [768,768] -> bf16
        gemm_k<0, false, false><<<dim3(32, 12, 1), 256, 0, stream>>>(
            XB, EMB, 0, 0, Wq, EMB, oW, 0, 0, QB, EMB, 0, 0, EMB, 0.f, nullptr, flag);
        gemm_k<0, false, false><<<dim3(32, 12, 1), 256, 0, stream>>>(
            XB, EMB, 0, 0, Wk, EMB, oW, 0, 0, KB, EMB, 0, 0, EMB, 0.f, nullptr, flag);
        gemm_k<0, false, false><<<dim3(32, 12, 1), 256, 0, stream>>>(
            XB, EMB, 0, 0, Wv, EMB, oW, 0, 0, VB, EMB, 0, 0, EMB, 0.f, nullptr, flag);

        // fused attention: scores+mask+softmax+probs-out+PV
        attn_k<<<dim3(SEQ / 16, BATCH * HEADS), 256, 0, stream>>>(
            QB, KB, VB, CTXB, d_out, probs_off, pad, flag);

        // attn out projection -> fp32 PRJ, then LN1
        gemm_k<2, false, false><<<dim3(32, 12, 1), 256, 0, stream>>>(
            CTXB, EMB, 0, 0, Wo, EMB, oW, 0, 0, PRJ, EMB, 0, 0, EMB, 0.f, nullptr, flag);
        ln_k<<<dim3((int)BS), 256, 0, stream>>>(PRJ, X, XB, g1, oLN, b1, oLN, flag);

        // FFN: relu(X W1) W2, then LN2
        gemm_k<1, false, false><<<dim3(32, 48, 1), 256, 0, stream>>>(
            XB, EMB, 0, 0, W1, DFF, oF1, 0, 0, HB, DFF, 0, 0, EMB, 0.f, nullptr, flag);
        gemm_k<2, false, false><<<dim3(32, 12, 1), 256, 0, stream>>>(
            HB, DFF, 0, 0, W2, EMB, oF2, 0, 0, PRJ, EMB, 0, 0, DFF, 0.f, nullptr, flag);
        ln_k<<<dim3((int)BS), 256, 0, stream>>>(PRJ, X, XB, g2, oLN, b2, oLN, flag);
    }

    copyout_k<<<dim3((int)(BSE / 256)), 256, 0, stream>>>(X, d_out, flag);
}

// Round 2
// 2006.424 us; speedup vs baseline: 1.7681x; 1.6865x over previous
//
#include <hip/hip_runtime.h>
#include <hip/hip_bf16.h>

#define LYR  6
#define BATCH 2
#define TOK  64
#define SEQ  1024
#define EMB  768
#define HEADS 12
#define HDK  64
#define DFF  3072
#define QKVN 2304   // 3*EMB, fused QKV output width

typedef __bf16 bf16_t;
typedef __bf16 bf16x8 __attribute__((ext_vector_type(8)));
typedef float  f32x4  __attribute__((ext_vector_type(4)));
typedef unsigned int u32;

// async global->LDS, 16B per lane; LDS dest = wave-uniform base + lane*16
#define GLDS16(g, l) __builtin_amdgcn_global_load_lds( \
    (const __attribute__((address_space(1))) u32*)(g), \
    (__attribute__((address_space(3))) u32*)(l), 16, 0, 0)

static __device__ __forceinline__ unsigned short bfbits(float f) {
    bf16_t b = (bf16_t)f; return *(unsigned short*)&b;
}
static __device__ __forceinline__ float loadf(const void* p, size_t e, int f32) {
    if (f32) return ((const float*)p)[e];
    return (float)((const bf16_t*)p)[e];
}
static __device__ __forceinline__ ushort4 load4bf(const void* p, size_t e, int f32) {
    if (f32) {
        float4 f = *(const float4*)((const float*)p + e);
        ushort4 u; u.x = bfbits(f.x); u.y = bfbits(f.y); u.z = bfbits(f.z); u.w = bfbits(f.w);
        return u;
    }
    return *(const ushort4*)((const unsigned short*)p + e);
}

// ---------------------------------------------------------------------------
// dtype detector: scan first 4096 16-bit chunks of Wq as bf16.
// ---------------------------------------------------------------------------
__global__ __launch_bounds__(256)
void detect_k(const void* w, int* flag)
{
    __shared__ int bad;
    if (threadIdx.x == 0) bad = 0;
    __syncthreads();
    const unsigned short* p = (const unsigned short*)w;
    int local = 0;
    for (int i = threadIdx.x; i < 4096; i += 256) {
        float v = (float)(*(const bf16_t*)&p[i]);
        if (!(v < 1e3f && v > -1e3f)) local = 1;   // catches NaN too
    }
    if (local) atomicOr(&bad, 1);
    __syncthreads();
    if (threadIdx.x == 0) *flag = bad;
}

// ---------------------------------------------------------------------------
// Weight transpose: src [L][K][N] (bf16 or fp32 per flag) -> dst bf16 [L][N][K]
// 64x64 tiles, vectorized both phases.  drow0: row offset in dst (QKV concat).
// ---------------------------------------------------------------------------
__global__ __launch_bounds__(256)
void transp_k(const void* __restrict__ src, bf16_t* __restrict__ dst,
              int K, int N, long sstride, long dstride, long drow0, long dld,
              const int* __restrict__ flagp)
{
    __shared__ unsigned short sm[64][68];
    const int f32 = *flagp;
    const int l  = blockIdx.z;
    const int n0 = blockIdx.x * 64;
    const int k0 = blockIdx.y * 64;
    const int tid = threadIdx.x;
    const int rr = tid >> 4;       // 0..15
    const int cc = tid & 15;       // 0..15 (chunk of 4 elems)

    const size_t sb = (size_t)l * sstride;
#pragma unroll
    for (int p = 0; p < 4; p++) {
        const int kr = rr + p * 16;
        ushort4 u = load4bf(src, sb + (size_t)(k0 + kr) * N + n0 + cc * 4, f32);
        *(ushort4*)&sm[kr][cc * 4] = u;
    }
    __syncthreads();
    const size_t db = (size_t)l * dstride;
#pragma unroll
    for (int p = 0; p < 4; p++) {
        const int r2 = rr + p * 16;          // n-offset within tile
        ushort4 v;
        v.x = sm[cc * 4 + 0][r2];
        v.y = sm[cc * 4 + 1][r2];
        v.z = sm[cc * 4 + 2][r2];
        v.w = sm[cc * 4 + 3][r2];
        *(ushort4*)&dst[db + (size_t)(drow0 + n0 + r2) * dld + k0 + cc * 4] = v;
    }
}

// ---------------------------------------------------------------------------
// m97-style GEMM: C[M][ldc] = A[M][K](bf16,lda) * BT[N][K]^T (bf16, ldb=K).
// 128x64 tile, BK=32, global_load_lds(16B) staging, 8 MFMA/wave per k-step.
// EPI: 0 = bf16 store, 1 = bf16 relu, 2 = fp32
// ---------------------------------------------------------------------------
template<int EPI>
__global__ __launch_bounds__(256)
void gemm_k(const bf16_t* __restrict__ A, long lda,
            const bf16_t* __restrict__ BT, long ldb,
            void* __restrict__ C, long ldc, int K)
{
    __shared__ __align__(16) unsigned short As[128 * 32];
    __shared__ __align__(16) unsigned short Bs[64 * 32];

    const int tid  = threadIdx.x;
    const int lane = tid & 63;
    const int wave = tid >> 6;
    const int bm = blockIdx.x * 128;
    const int bn = blockIdx.y * 64;

    const int srow = lane >> 2;          // row within 16-row staging chunk
    const int scb  = (lane & 3) * 16;    // byte col within 64B row

    const char* gA = (const char*)A;
    const char* gB = (const char*)BT;

    f32x4 acc[2][4];
#pragma unroll
    for (int af = 0; af < 2; af++)
#pragma unroll
        for (int bf = 0; bf < 4; bf++) acc[af][bf] = (f32x4){0.f, 0.f, 0.f, 0.f};

    const int l15 = lane & 15, l4 = lane >> 4;

    for (int k0 = 0; k0 < K; k0 += 32) {
        // stage A tile [128][32] (8KB): 2 rounds x 4 waves x 1KB
#pragma unroll
        for (int j = 0; j < 2; j++) {
            const int rb = (j * 4 + wave) * 16;
            const char* g = gA + ((size_t)(bm + rb + srow) * lda + k0) * 2 + scb;
            GLDS16(g, &As[rb * 32]);
        }
        // stage B tile [64][32] (4KB): 1 round
        {
            const int rb = wave * 16;
            const char* g = gB + ((size_t)(bn + rb + srow) * ldb + k0) * 2 + scb;
            GLDS16(g, &Bs[rb * 32]);
        }
        __syncthreads();

        const bf16x8 a0 = *(const bf16x8*)&As[(wave * 32 + l15) * 32 + l4 * 8];
        const bf16x8 a1 = *(const bf16x8*)&As[(wave * 32 + 16 + l15) * 32 + l4 * 8];
#pragma unroll
        for (int bf = 0; bf < 4; bf++) {
            const bf16x8 bv = *(const bf16x8*)&Bs[(bf * 16 + l15) * 32 + l4 * 8];
            acc[0][bf] = __builtin_amdgcn_mfma_f32_16x16x32_bf16(a0, bv, acc[0][bf], 0, 0, 0);
            acc[1][bf] = __builtin_amdgcn_mfma_f32_16x16x32_bf16(a1, bv, acc[1][bf], 0, 0, 0);
        }
        __syncthreads();
    }

#pragma unroll
    for (int af = 0; af < 2; af++) {
#pragma unroll
        for (int bf = 0; bf < 4; bf++) {
#pragma unroll
            for (int r = 0; r < 4; r++) {
                const int row = bm + wave * 32 + af * 16 + l4 * 4 + r;
                const int col = bn + bf * 16 + l15;
                const float v = acc[af][bf][r];
                const size_t idx = (size_t)row * ldc + col;
                if constexpr (EPI == 0) {
                    ((bf16_t*)C)[idx] = (bf16_t)v;
                } else if constexpr (EPI == 1) {
                    ((bf16_t*)C)[idx] = (bf16_t)(v > 0.f ? v : 0.f);
                } else {
                    ((float*)C)[idx] = v;
                }
            }
        }
    }
}

__global__ __launch_bounds__(256)
void posadd_k(const void* __restrict__ x, const void* __restrict__ tp,
              const void* __restrict__ sp, float* __restrict__ X,
              bf16_t* __restrict__ XB, int* __restrict__ pad,
              const int* __restrict__ flagp)
{
    const int f32 = *flagp;
    const int row = blockIdx.x;              // b*S + s
    const int s = row % SEQ;
    const int f = s / TOK, tt = s % TOK;
    const int tid = threadIdx.x;
#pragma unroll
    for (int i = 0; i < 3; i++) {
        int e = tid + i * 256;
        float v = loadf(x, (size_t)row * EMB + e, f32)
                + loadf(tp, (size_t)f * EMB + e, f32)
                + loadf(sp, (size_t)tt * EMB + e, f32);
        X[(size_t)row * EMB + e]  = v;
        XB[(size_t)row * EMB + e] = (bf16_t)v;
        if (e == 0) pad[row] = (v == 0.0f) ? 1 : 0;
    }
}

// ---------------------------------------------------------------------------
// Fused attention: QKV is the fused [B*S][2304] buffer (Q|K|V), row stride ldx.
// scores (bf16 MFMA, fp32 acc, in registers) -> softmax -> probs to d_out +
// LDS (bf16) -> PV (bf16 MFMA) -> ctx.  One block = 16 query rows of one (b,h).
// ---------------------------------------------------------------------------
__global__ __launch_bounds__(256)
void attn_k(const bf16_t* __restrict__ QKV, long ldx, bf16_t* __restrict__ CTX,
            void* __restrict__ outp, long probs_off,
            const int* __restrict__ pad, const int* __restrict__ flagp)
{
    __shared__ __align__(16) unsigned short KV[64][72];   // K tile, then V^T tile
    __shared__ __align__(16) unsigned short P[16][1032];  // probs bf16 [row][col]
    __shared__ float redm[4][16];
    __shared__ float reds[4][16];

    const int f32 = *flagp;
    const int bx  = blockIdx.x;              // query tile (16 rows)
    const int z   = blockIdx.y;              // b*H + h
    const int bq  = z / HEADS, h = z % HEADS;
    const int tid = threadIdx.x;
    const int lane = tid & 63;
    const int w    = tid >> 6;
    const int l15  = lane & 15;
    const int l4   = lane >> 4;

    const size_t xoff = (size_t)bq * SEQ * ldx + (size_t)h * HDK;
    const bf16_t* Qp = QKV + xoff;
    const bf16_t* Kp = QKV + xoff + EMB;
    const bf16_t* Vp = QKV + xoff + 2 * EMB;
    const int row0 = bx * 16;
    const int nt   = (bx >> 2) + 1;          // causal col-tile count (of 16)

    // Q fragments (A operand): rows row0+l15, k = ks*32 + l4*8
    bf16x8 aq0, aq1;
    {
        const bf16_t* qp = Qp + (size_t)(row0 + l15) * ldx + l4 * 8;
        aq0 = *(const bf16x8*)qp;
        aq1 = *(const bf16x8*)(qp + 32);
    }

    f32x4 sc[16];   // scores: wave w owns cols ct*64 + w*16 + l15, rows l4*4+r

    // ---- QK^T -------------------------------------------------------------
#pragma unroll
    for (int ct = 0; ct < 16; ct++) {
        if (ct < nt) {
            {
                const int tk = tid >> 3, d0 = (tid & 7) * 8;
                const bf16_t* kp = Kp + (size_t)(ct * 64 + tk) * ldx + d0;
                *(uint4*)&KV[tk][d0]      = *(const uint4*)kp;
                *(uint4*)&KV[tk + 32][d0] = *(const uint4*)(kp + (size_t)32 * ldx);
            }
            __syncthreads();
            bf16x8 b0 = *(const bf16x8*)&KV[w * 16 + l15][l4 * 8];
            bf16x8 b1 = *(const bf16x8*)&KV[w * 16 + l15][32 + l4 * 8];
            f32x4 a = (f32x4){0.f, 0.f, 0.f, 0.f};
            a = __builtin_amdgcn_mfma_f32_16x16x32_bf16(aq0, b0, a, 0, 0, 0);
            a = __builtin_amdgcn_mfma_f32_16x16x32_bf16(aq1, b1, a, 0, 0, 0);
            const int col = ct * 64 + w * 16 + l15;
            const int pd  = pad[bq * SEQ + col];
#pragma unroll
            for (int r = 0; r < 4; r++) {
                float v = a[r] * 0.125f;
                if (col > row0 + l4 * 4 + r || pd) v = -1e9f;
                sc[ct][r] = v;
            }
            __syncthreads();
        }
    }

    // ---- softmax ----------------------------------------------------------
    float m4[4], s4[4];
#pragma unroll
    for (int r = 0; r < 4; r++) m4[r] = -3.0e38f;
#pragma unroll
    for (int ct = 0; ct < 16; ct++)
        if (ct < nt) {
#pragma unroll
            for (int r = 0; r < 4; r++) m4[r] = fmaxf(m4[r], sc[ct][r]);
        }
#pragma unroll
    for (int r = 0; r < 4; r++) {
        m4[r] = fmaxf(m4[r], __shfl_xor(m4[r], 1, 64));
        m4[r] = fmaxf(m4[r], __shfl_xor(m4[r], 2, 64));
        m4[r] = fmaxf(m4[r], __shfl_xor(m4[r], 4, 64));
        m4[r] = fmaxf(m4[r], __shfl_xor(m4[r], 8, 64));
    }
    if (l15 == 0) {
#pragma unroll
        for (int r = 0; r < 4; r++) redm[w][l4 * 4 + r] = m4[r];
    }
    __syncthreads();
#pragma unroll
    for (int r = 0; r < 4; r++) {
        const int row = l4 * 4 + r;
        m4[r] = fmaxf(fmaxf(redm[0][row], redm[1][row]),
                      fmaxf(redm[2][row], redm[3][row]));
        s4[r] = 0.f;
    }
#pragma unroll
    for (int ct = 0; ct < 16; ct++)
        if (ct < nt) {
#pragma unroll
            for (int r = 0; r < 4; r++) {
                float e = __expf(sc[ct][r] - m4[r]);
                sc[ct][r] = e;
                s4[r] += e;
            }
        }
#pragma unroll
    for (int r = 0; r < 4; r++) {
        s4[r] += __shfl_xor(s4[r], 1, 64);
        s4[r] += __shfl_xor(s4[r], 2, 64);
        s4[r] += __shfl_xor(s4[r], 4, 64);
        s4[r] += __shfl_xor(s4[r], 8, 64);
    }
    if (l15 == 0) {
#pragma unroll
        for (int r = 0; r < 4; r++) reds[w][l4 * 4 + r] = s4[r];
    }
    __syncthreads();
    float inv[4];
#pragma unroll
    for (int r = 0; r < 4; r++) {
        const int row = l4 * 4 + r;
        inv[r] = 1.0f / (reds[0][row] + reds[1][row] + reds[2][row] + reds[3][row]);
    }

    // ---- write probs: d_out (dtype-branched) + P_lds (bf16 for PV) --------
    const size_t obase = (size_t)probs_off + ((size_t)z * SEQ + row0) * SEQ;
#pragma unroll
    for (int ct = 0; ct < 16; ct++) {
        if (ct < nt) {
            const int col = ct * 64 + w * 16 + l15;
#pragma unroll
            for (int r = 0; r < 4; r++) {
                const int row = l4 * 4 + r;
                const float p  = sc[ct][r] * inv[r];
                const float p2 = __shfl_xor(p, 1, 64);   // col-neighbor value
                if (!(lane & 1)) {
                    const unsigned int pk =
                        ((unsigned int)bfbits(p2) << 16) | bfbits(p);
                    *(unsigned int*)&P[row][col] = pk;   // col even here
                    if (!f32)
                        *(unsigned int*)((unsigned short*)outp + obase +
                                         (size_t)row * SEQ + col) = pk;
                }
                if (f32)
                    ((float*)outp)[obase + (size_t)row * SEQ + col] = p;
            }
        }
    }
    // causal tail: exact zeros
    {
        const int c0 = nt * 64;
        if (c0 < SEQ) {
            const int rr = tid >> 4, ii = tid & 15;
            if (f32) {
                float* op = (float*)outp + obase + (size_t)rr * SEQ;
                const float4 zz = {0.f, 0.f, 0.f, 0.f};
                for (int c = c0 + ii * 4; c < SEQ; c += 64) *(float4*)(op + c) = zz;
            } else {
                unsigned short* op = (unsigned short*)outp + obase + (size_t)rr * SEQ;
                const uint4 zz = {0u, 0u, 0u, 0u};
                for (int c = c0 + ii * 8; c < SEQ; c += 128) *(uint4*)(op + c) = zz;
            }
        }
    }

    // ---- PV ---------------------------------------------------------------
    f32x4 co = (f32x4){0.f, 0.f, 0.f, 0.f};
#pragma unroll
    for (int kt = 0; kt < 16; kt++) {
        if (kt < nt) {
            __syncthreads();       // KV reads from prev tile done; P writes done
#pragma unroll
            for (int i = 0; i < 4; i++) {
                const int e = (tid + i * 256) * 4;
                const int kk = e >> 6, n = e & 63;
                const ushort4 u = *(const ushort4*)
                    ((const unsigned short*)Vp + (size_t)(kt * 64 + kk) * ldx + n);
                KV[n + 0][kk] = u.x; KV[n + 1][kk] = u.y;
                KV[n + 2][kk] = u.z; KV[n + 3][kk] = u.w;
            }
            __syncthreads();
            bf16x8 a0 = *(const bf16x8*)&P[l15][kt * 64 + l4 * 8];
            bf16x8 a1 = *(const bf16x8*)&P[l15][kt * 64 + 32 + l4 * 8];
            bf16x8 b0 = *(const bf16x8*)&KV[w * 16 + l15][l4 * 8];
            bf16x8 b1 = *(const bf16x8*)&KV[w * 16 + l15][32 + l4 * 8];
            co = __builtin_amdgcn_mfma_f32_16x16x32_bf16(a0, b0, co, 0, 0, 0);
            co = __builtin_amdgcn_mfma_f32_16x16x32_bf16(a1, b1, co, 0, 0, 0);
        }
    }
    bf16_t* cp = CTX + (size_t)bq * SEQ * EMB + (size_t)h * HDK
               + (size_t)row0 * EMB + w * 16 + l15;
#pragma unroll
    for (int r = 0; r < 4; r++)
        cp[(size_t)(l4 * 4 + r) * EMB] = (bf16_t)co[r];
}

static __device__ __forceinline__ float bsum(float v, float* red)
{
#pragma unroll
    for (int off = 32; off; off >>= 1) v += __shfl_down(v, off, 64);
    const int lane = threadIdx.x & 63, w = threadIdx.x >> 6;
    __syncthreads();
    if (lane == 0) red[w] = v;
    __syncthreads();
    return red[0] + red[1] + red[2] + red[3];
}

__global__ __launch_bounds__(256)
void ln_k(const float* __restrict__ proj, float* __restrict__ X,
          bf16_t* __restrict__ XB, const void* __restrict__ g, long goff,
          const void* __restrict__ bb, long boff2, const int* __restrict__ flagp)
{
    const int f32 = *flagp;
    const int row = blockIdx.x;
    const float* p = proj + (size_t)row * EMB;
    float* x  = X  + (size_t)row * EMB;
    bf16_t* xb = XB + (size_t)row * EMB;
    const int tid = threadIdx.x;
    __shared__ float red[4];

    float v[3];
    float sum = 0.f;
#pragma unroll
    for (int i = 0; i < 3; i++) { int e = tid + i * 256; v[i] = p[e] + x[e]; sum += v[i]; }
    sum = bsum(sum, red);
    const float mean = sum * (1.0f / EMB);

    float vs = 0.f;
#pragma unroll
    for (int i = 0; i < 3; i++) { float d = v[i] - mean; vs += d * d; }
    vs = bsum(vs, red);
    const float rstd = rsqrtf(vs * (1.0f / EMB) + 1e-5f);

#pragma unroll
    for (int i = 0; i < 3; i++) {
        int e = tid + i * 256;
        float y = (v[i] - mean) * rstd * loadf(g, goff + e, f32) + loadf(bb, boff2 + e, f32);
        x[e] = y;
        xb[e] = (bf16_t)y;
    }
}

__global__ __launch_bounds__(256)
void copyout_k(const float* __restrict__ X, void* __restrict__ outp,
               const int* __restrict__ flagp)
{
    const int f32 = *flagp;
    int i = blockIdx.x * 256 + threadIdx.x;
    float v = X[i];
    if (f32) ((float*)outp)[i] = v;
    else     ((bf16_t*)outp)[i] = (bf16_t)v;
}

// ---------------------------------------------------------------------------
extern "C" void kernel_launch(void* const* d_in, const int* in_sizes, int n_in,
                              void* d_out, int out_size, void* d_ws, size_t ws_size,
                              hipStream_t stream)
{
    const void* x  = d_in[0];
    const void* tp = d_in[1];
    const void* sp = d_in[2];
    const void* Wq = d_in[3];
    const void* Wk = d_in[4];
    const void* Wv = d_in[5];
    const void* Wo = d_in[6];
    const void* g1 = d_in[7];
    const void* b1 = d_in[8];
    const void* W1 = d_in[9];
    const void* W2 = d_in[10];
    const void* g2 = d_in[11];
    const void* b2 = d_in[12];

    const size_t BS   = (size_t)BATCH * SEQ;                 // 2048
    const size_t BSE  = BS * EMB;                             // 1.57M
    const size_t ATT1 = (size_t)BATCH * HEADS * SEQ * SEQ;    // 25.2M / layer

    char* ws = (char*)d_ws;
    size_t off = 0;
    auto alloc = [&](size_t bytes) { void* p = ws + off; off += (bytes + 255) & ~255ULL; return p; };

    float*  X     = (float*)alloc(BSE * 4);
    bf16_t* XB    = (bf16_t*)alloc(BSE * 2);
    bf16_t* QKV   = (bf16_t*)alloc(BS * QKVN * 2);
    bf16_t* CTXB  = (bf16_t*)alloc(BSE * 2);
    bf16_t* HB    = (bf16_t*)alloc(BS * DFF * 2);
    float*  PRJ   = (float*)alloc(BSE * 4);
    bf16_t* WqkvT = (bf16_t*)alloc((size_t)LYR * QKVN * EMB * 2);
    bf16_t* WoT   = (bf16_t*)alloc((size_t)LYR * EMB * EMB * 2);
    bf16_t* W1T   = (bf16_t*)alloc((size_t)LYR * DFF * EMB * 2);
    bf16_t* W2T   = (bf16_t*)alloc((size_t)LYR * EMB * DFF * 2);
    int*    pad   = (int*)alloc(BS * 4);
    int*    flag  = (int*)alloc(256);

    detect_k<<<dim3(1), 256, 0, stream>>>(Wq, flag);

    // one-time weight transposes -> bf16 [N][K]
    transp_k<<<dim3(12, 12, LYR), 256, 0, stream>>>(
        Wq, WqkvT, EMB, EMB, (long)EMB * EMB, (long)QKVN * EMB, 0, EMB, flag);
    transp_k<<<dim3(12, 12, LYR), 256, 0, stream>>>(
        Wk, WqkvT, EMB, EMB, (long)EMB * EMB, (long)QKVN * EMB, EMB, EMB, flag);
    transp_k<<<dim3(12, 12, LYR), 256, 0, stream>>>(
        Wv, WqkvT, EMB, EMB, (long)EMB * EMB, (long)QKVN * EMB, 2 * EMB, EMB, flag);
    transp_k<<<dim3(12, 12, LYR), 256, 0, stream>>>(
        Wo, WoT, EMB, EMB, (long)EMB * EMB, (long)EMB * EMB, 0, EMB, flag);
    transp_k<<<dim3(DFF / 64, 12, LYR), 256, 0, stream>>>(
        W1, W1T, EMB, DFF, (long)EMB * DFF, (long)DFF * EMB, 0, EMB, flag);
    transp_k<<<dim3(12, DFF / 64, LYR), 256, 0, stream>>>(
        W2, W2T, DFF, EMB, (long)DFF * EMB, (long)EMB * DFF, 0, DFF, flag);

    posadd_k<<<dim3((int)BS), 256, 0, stream>>>(x, tp, sp, X, XB, pad, flag);

    for (int l = 0; l < LYR; l++) {
        const long probs_off = (long)(BSE + (size_t)l * ATT1);

        // fused QKV projection: [2048,768] x [768,2304] -> bf16 QKV
        gemm_k<0><<<dim3(16, QKVN / 64), 256, 0, stream>>>(
            XB, EMB, WqkvT + (size_t)l * QKVN * EMB, EMB, QKV, QKVN, EMB);

        // fused attention: scores+mask+softmax+probs-out+PV
        attn_k<<<dim3(SEQ / 16, BATCH * HEADS), 256, 0, stream>>>(
            QKV, QKVN, CTXB, d_out, probs_off, pad, flag);

        // attn out projection -> fp32 PRJ, then LN1
        gemm_k<2><<<dim3(16, EMB / 64), 256, 0, stream>>>(
            CTXB, EMB, WoT + (size_t)l * EMB * EMB, EMB, PRJ, EMB, EMB);
        ln_k<<<dim3((int)BS), 256, 0, stream>>>(PRJ, X, XB, g1, (long)l * EMB, b1, (long)l * EMB, flag);

        // FFN: relu(X W1) W2, then LN2
        gemm_k<1><<<dim3(16, DFF / 64), 256, 0, stream>>>(
            XB, EMB, W1T + (size_t)l * DFF * EMB, EMB, HB, DFF, EMB);
        gemm_k<2><<<dim3(16, EMB / 64), 256, 0, stream>>>(
            HB, DFF, W2T + (size_t)l * EMB * DFF, DFF, PRJ, EMB, DFF);
        ln_k<<<dim3((int)BS), 256, 0, stream>>>(PRJ, X, XB, g2, (long)l * EMB, b2, (long)l * EMB, flag);
    }

    copyout_k<<<dim3((int)(BSE / 256)), 256, 0, stream>>>(X, d_out, flag);
}

// Round 3
// 1910.308 us; speedup vs baseline: 1.8570x; 1.0503x over previous
//
#include <hip/hip_runtime.h>
#include <hip/hip_bf16.h>

#define LYR  6
#define BATCH 2
#define TOK  64
#define SEQ  1024
#define EMB  768
#define HEADS 12
#define HDK  64
#define DFF  3072
#define QKVN 2304   // 3*EMB, fused QKV output width

typedef __bf16 bf16_t;
typedef __bf16 bf16x8 __attribute__((ext_vector_type(8)));
typedef float  f32x4  __attribute__((ext_vector_type(4)));
typedef unsigned int u32;

// async global->LDS, 16B per lane; LDS dest = wave-uniform base + lane*16
#define GLDS16(g, l) __builtin_amdgcn_global_load_lds( \
    (const __attribute__((address_space(1))) u32*)(g), \
    (__attribute__((address_space(3))) u32*)(l), 16, 0, 0)

static __device__ __forceinline__ unsigned short bfbits(float f) {
    bf16_t b = (bf16_t)f; return *(unsigned short*)&b;
}
static __device__ __forceinline__ float loadf(const void* p, size_t e, int f32) {
    if (f32) return ((const float*)p)[e];
    return (float)((const bf16_t*)p)[e];
}
static __device__ __forceinline__ ushort4 load4bf(const void* p, size_t e, int f32) {
    if (f32) {
        float4 f = *(const float4*)((const float*)p + e);
        ushort4 u; u.x = bfbits(f.x); u.y = bfbits(f.y); u.z = bfbits(f.z); u.w = bfbits(f.w);
        return u;
    }
    return *(const ushort4*)((const unsigned short*)p + e);
}

// ---------------------------------------------------------------------------
// dtype detector: scan first 4096 16-bit chunks of Wq as bf16.
// ---------------------------------------------------------------------------
__global__ __launch_bounds__(256)
void detect_k(const void* w, int* flag)
{
    __shared__ int bad;
    if (threadIdx.x == 0) bad = 0;
    __syncthreads();
    const unsigned short* p = (const unsigned short*)w;
    int local = 0;
    for (int i = threadIdx.x; i < 4096; i += 256) {
        float v = (float)(*(const bf16_t*)&p[i]);
        if (!(v < 1e3f && v > -1e3f)) local = 1;   // catches NaN too
    }
    if (local) atomicOr(&bad, 1);
    __syncthreads();
    if (threadIdx.x == 0) *flag = bad;
}

// ---------------------------------------------------------------------------
// Weight transpose: src [L][K][N] (bf16 or fp32 per flag) -> dst bf16 [L][N][K]
// ---------------------------------------------------------------------------
__global__ __launch_bounds__(256)
void transp_k(const void* __restrict__ src, bf16_t* __restrict__ dst,
              int K, int N, long sstride, long dstride, long drow0, long dld,
              const int* __restrict__ flagp)
{
    __shared__ unsigned short sm[64][68];
    const int f32 = *flagp;
    const int l  = blockIdx.z;
    const int n0 = blockIdx.x * 64;
    const int k0 = blockIdx.y * 64;
    const int tid = threadIdx.x;
    const int rr = tid >> 4;       // 0..15
    const int cc = tid & 15;       // 0..15 (chunk of 4 elems)

    const size_t sb = (size_t)l * sstride;
#pragma unroll
    for (int p = 0; p < 4; p++) {
        const int kr = rr + p * 16;
        ushort4 u = load4bf(src, sb + (size_t)(k0 + kr) * N + n0 + cc * 4, f32);
        *(ushort4*)&sm[kr][cc * 4] = u;
    }
    __syncthreads();
    const size_t db = (size_t)l * dstride;
#pragma unroll
    for (int p = 0; p < 4; p++) {
        const int r2 = rr + p * 16;          // n-offset within tile
        ushort4 v;
        v.x = sm[cc * 4 + 0][r2];
        v.y = sm[cc * 4 + 1][r2];
        v.z = sm[cc * 4 + 2][r2];
        v.w = sm[cc * 4 + 3][r2];
        *(ushort4*)&dst[db + (size_t)(drow0 + n0 + r2) * dld + k0 + cc * 4] = v;
    }
}

// ---------------------------------------------------------------------------
// V transpose per layer: V slice of QKV [B*S][2304] -> VT [B*H][64][1024]
// ---------------------------------------------------------------------------
__global__ __launch_bounds__(256)
void vtr_k(const bf16_t* __restrict__ QKV, bf16_t* __restrict__ VT)
{
    __shared__ unsigned short sm[64][68];
    const int z  = blockIdx.y;            // b*H + h
    const int s0 = blockIdx.x * 64;
    const int bq = z / HEADS, h = z % HEADS;
    const int tid = threadIdx.x;
    const int rr = tid >> 4, cc = tid & 15;
    const unsigned short* src = (const unsigned short*)QKV
        + (size_t)bq * SEQ * QKVN + 2 * EMB + (size_t)h * HDK;
#pragma unroll
    for (int p = 0; p < 4; p++) {
        const int s = rr + p * 16;
        *(ushort4*)&sm[s][cc * 4] =
            *(const ushort4*)(src + (size_t)(s0 + s) * QKVN + cc * 4);
    }
    __syncthreads();
    unsigned short* dst = (unsigned short*)VT + (size_t)z * HDK * SEQ;
#pragma unroll
    for (int p = 0; p < 4; p++) {
        const int d = rr + p * 16;
        ushort4 v;
        v.x = sm[cc * 4 + 0][d];
        v.y = sm[cc * 4 + 1][d];
        v.z = sm[cc * 4 + 2][d];
        v.w = sm[cc * 4 + 3][d];
        *(ushort4*)(dst + (size_t)d * SEQ + s0 + cc * 4) = v;
    }
}

// ---------------------------------------------------------------------------
// m97-style GEMM, 128x64 tile: C = A[M][K] * BT[N][K]^T.  8 MFMA/wave/k-step.
// EPI: 0 = bf16 store, 1 = bf16 relu, 2 = fp32
// ---------------------------------------------------------------------------
template<int EPI>
__global__ __launch_bounds__(256)
void gemm64_k(const bf16_t* __restrict__ A, long lda,
              const bf16_t* __restrict__ BT, long ldb,
              void* __restrict__ C, long ldc, int K)
{
    __shared__ __align__(16) unsigned short As[128 * 32];
    __shared__ __align__(16) unsigned short Bs[64 * 32];

    const int tid  = threadIdx.x;
    const int lane = tid & 63;
    const int wave = tid >> 6;
    const int bm = blockIdx.x * 128;
    const int bn = blockIdx.y * 64;
    const int srow = lane >> 2;
    const int scb  = (lane & 3) * 16;
    const int l15 = lane & 15, l4 = lane >> 4;

    const char* gA = (const char*)A;
    const char* gB = (const char*)BT;

    f32x4 acc[2][4];
#pragma unroll
    for (int af = 0; af < 2; af++)
#pragma unroll
        for (int bf = 0; bf < 4; bf++) acc[af][bf] = (f32x4){0.f, 0.f, 0.f, 0.f};

    for (int k0 = 0; k0 < K; k0 += 32) {
#pragma unroll
        for (int j = 0; j < 2; j++) {
            const int rb = (j * 4 + wave) * 16;
            const char* g = gA + ((size_t)(bm + rb + srow) * lda + k0) * 2 + scb;
            GLDS16(g, &As[rb * 32]);
        }
        {
            const int rb = wave * 16;
            const char* g = gB + ((size_t)(bn + rb + srow) * ldb + k0) * 2 + scb;
            GLDS16(g, &Bs[rb * 32]);
        }
        __syncthreads();

        const bf16x8 a0 = *(const bf16x8*)&As[(wave * 32 + l15) * 32 + l4 * 8];
        const bf16x8 a1 = *(const bf16x8*)&As[(wave * 32 + 16 + l15) * 32 + l4 * 8];
#pragma unroll
        for (int bf = 0; bf < 4; bf++) {
            const bf16x8 bv = *(const bf16x8*)&Bs[(bf * 16 + l15) * 32 + l4 * 8];
            acc[0][bf] = __builtin_amdgcn_mfma_f32_16x16x32_bf16(a0, bv, acc[0][bf], 0, 0, 0);
            acc[1][bf] = __builtin_amdgcn_mfma_f32_16x16x32_bf16(a1, bv, acc[1][bf], 0, 0, 0);
        }
        __syncthreads();
    }

#pragma unroll
    for (int af = 0; af < 2; af++) {
#pragma unroll
        for (int bf = 0; bf < 4; bf++) {
#pragma unroll
            for (int r = 0; r < 4; r++) {
                const int row = bm + wave * 32 + af * 16 + l4 * 4 + r;
                const int col = bn + bf * 16 + l15;
                const float v = acc[af][bf][r];
                const size_t idx = (size_t)row * ldc + col;
                if constexpr (EPI == 0) {
                    ((bf16_t*)C)[idx] = (bf16_t)v;
                } else if constexpr (EPI == 1) {
                    ((bf16_t*)C)[idx] = (bf16_t)(v > 0.f ? v : 0.f);
                } else {
                    ((float*)C)[idx] = v;
                }
            }
        }
    }
}

// ---------------------------------------------------------------------------
// m97-exact GEMM, 128x128 tile: 16 MFMA/wave/k-step, 16KB LDS.
// ---------------------------------------------------------------------------
template<int EPI>
__global__ __launch_bounds__(256)
void gemm128_k(const bf16_t* __restrict__ A, long lda,
               const bf16_t* __restrict__ BT, long ldb,
               void* __restrict__ C, long ldc, int K)
{
    __shared__ __align__(16) unsigned short As[128 * 32];
    __shared__ __align__(16) unsigned short Bs[128 * 32];

    const int tid  = threadIdx.x;
    const int lane = tid & 63;
    const int wave = tid >> 6;
    const int bm = blockIdx.x * 128;
    const int bn = blockIdx.y * 128;
    const int srow = lane >> 2;
    const int scb  = (lane & 3) * 16;
    const int l15 = lane & 15, l4 = lane >> 4;
    const int wr = wave >> 1, wc = wave & 1;

    const char* gA = (const char*)A;
    const char* gB = (const char*)BT;

    f32x4 acc[4][4];
#pragma unroll
    for (int m = 0; m < 4; m++)
#pragma unroll
        for (int n = 0; n < 4; n++) acc[m][n] = (f32x4){0.f, 0.f, 0.f, 0.f};

    for (int k0 = 0; k0 < K; k0 += 32) {
#pragma unroll
        for (int j = 0; j < 2; j++) {
            const int rb = (j * 4 + wave) * 16;
            const char* g = gA + ((size_t)(bm + rb + srow) * lda + k0) * 2 + scb;
            GLDS16(g, &As[rb * 32]);
        }
#pragma unroll
        for (int j = 0; j < 2; j++) {
            const int rb = (j * 4 + wave) * 16;
            const char* g = gB + ((size_t)(bn + rb + srow) * ldb + k0) * 2 + scb;
            GLDS16(g, &Bs[rb * 32]);
        }
        __syncthreads();

        bf16x8 a[4], b[4];
#pragma unroll
        for (int m = 0; m < 4; m++)
            a[m] = *(const bf16x8*)&As[(wr * 64 + m * 16 + l15) * 32 + l4 * 8];
#pragma unroll
        for (int n = 0; n < 4; n++)
            b[n] = *(const bf16x8*)&Bs[(wc * 64 + n * 16 + l15) * 32 + l4 * 8];
#pragma unroll
        for (int m = 0; m < 4; m++)
#pragma unroll
            for (int n = 0; n < 4; n++)
                acc[m][n] = __builtin_amdgcn_mfma_f32_16x16x32_bf16(a[m], b[n], acc[m][n], 0, 0, 0);
        __syncthreads();
    }

#pragma unroll
    for (int m = 0; m < 4; m++) {
#pragma unroll
        for (int n = 0; n < 4; n++) {
#pragma unroll
            for (int r = 0; r < 4; r++) {
                const int row = bm + wr * 64 + m * 16 + l4 * 4 + r;
                const int col = bn + wc * 64 + n * 16 + l15;
                const float v = acc[m][n][r];
                const size_t idx = (size_t)row * ldc + col;
                if constexpr (EPI == 0) {
                    ((bf16_t*)C)[idx] = (bf16_t)v;
                } else if constexpr (EPI == 1) {
                    ((bf16_t*)C)[idx] = (bf16_t)(v > 0.f ? v : 0.f);
                } else {
                    ((float*)C)[idx] = v;
                }
            }
        }
    }
}

__global__ __launch_bounds__(256)
void posadd_k(const void* __restrict__ x, const void* __restrict__ tp,
              const void* __restrict__ sp, float* __restrict__ X,
              bf16_t* __restrict__ XB, int* __restrict__ pad,
              const int* __restrict__ flagp)
{
    const int f32 = *flagp;
    const int row = blockIdx.x;              // b*S + s
    const int s = row % SEQ;
    const int f = s / TOK, tt = s % TOK;
    const int tid = threadIdx.x;
#pragma unroll
    for (int i = 0; i < 3; i++) {
        int e = tid + i * 256;
        float v = loadf(x, (size_t)row * EMB + e, f32)
                + loadf(tp, (size_t)f * EMB + e, f32)
                + loadf(sp, (size_t)tt * EMB + e, f32);
        X[(size_t)row * EMB + e]  = v;
        XB[(size_t)row * EMB + e] = (bf16_t)v;
        if (e == 0) pad[row] = (v == 0.0f) ? 1 : 0;
    }
}

// ---------------------------------------------------------------------------
// Fused attention v2: barrier-light.  K frags direct from global (L2),
// V frags from pre-transposed VT (global, contiguous).  P via LDS.
// 3 __syncthreads per block (vs ~36 in v1).
// ---------------------------------------------------------------------------
__global__ __launch_bounds__(256)
void attn_k(const bf16_t* __restrict__ QKV, const bf16_t* __restrict__ VT,
            bf16_t* __restrict__ CTX, void* __restrict__ outp, long probs_off,
            const int* __restrict__ pad, const int* __restrict__ flagp)
{
    __shared__ __align__(16) unsigned short P[16][1032];  // probs bf16 [row][col]
    __shared__ float redm[4][16];
    __shared__ float reds[4][16];

    const int f32 = *flagp;
    const int bx  = blockIdx.x;              // query tile (16 rows)
    const int z   = blockIdx.y;              // b*H + h
    const int bq  = z / HEADS, h = z % HEADS;
    const int tid = threadIdx.x;
    const int lane = tid & 63;
    const int w    = tid >> 6;
    const int l15  = lane & 15;
    const int l4   = lane >> 4;

    const size_t qoff = (size_t)bq * SEQ * QKVN + (size_t)h * HDK;
    const bf16_t* Qp = QKV + qoff;
    const bf16_t* Kp = QKV + qoff + EMB;
    const bf16_t* Vt = VT + (size_t)z * HDK * SEQ;
    const int row0 = bx * 16;
    const int nt   = (bx >> 2) + 1;          // causal col-tile count (of 16)

    // Q fragments (A operand): rows row0+l15, k = ks*32 + l4*8
    bf16x8 aq0, aq1;
    {
        const bf16_t* qp = Qp + (size_t)(row0 + l15) * QKVN + l4 * 8;
        aq0 = *(const bf16x8*)qp;
        aq1 = *(const bf16x8*)(qp + 32);
    }

    f32x4 sc[16];   // scores: wave w owns cols ct*64 + w*16 + l15, rows l4*4+r

    // ---- QK^T: no barriers, K frags straight from L2 ----------------------
#pragma unroll
    for (int ct = 0; ct < 16; ct++) {
        if (ct < nt) {
            const bf16_t* kp = Kp + (size_t)(ct * 64 + w * 16 + l15) * QKVN + l4 * 8;
            const bf16x8 b0 = *(const bf16x8*)kp;
            const bf16x8 b1 = *(const bf16x8*)(kp + 32);
            f32x4 a = (f32x4){0.f, 0.f, 0.f, 0.f};
            a = __builtin_amdgcn_mfma_f32_16x16x32_bf16(aq0, b0, a, 0, 0, 0);
            a = __builtin_amdgcn_mfma_f32_16x16x32_bf16(aq1, b1, a, 0, 0, 0);
            const int col = ct * 64 + w * 16 + l15;
            const int pd  = pad[bq * SEQ + col];
#pragma unroll
            for (int r = 0; r < 4; r++) {
                float v = a[r] * 0.125f;
                if (col > row0 + l4 * 4 + r || pd) v = -1e9f;
                sc[ct][r] = v;
            }
        }
    }

    // ---- softmax ----------------------------------------------------------
    float m4[4], s4[4];
#pragma unroll
    for (int r = 0; r < 4; r++) m4[r] = -3.0e38f;
#pragma unroll
    for (int ct = 0; ct < 16; ct++)
        if (ct < nt) {
#pragma unroll
            for (int r = 0; r < 4; r++) m4[r] = fmaxf(m4[r], sc[ct][r]);
        }
#pragma unroll
    for (int r = 0; r < 4; r++) {
        m4[r] = fmaxf(m4[r], __shfl_xor(m4[r], 1, 64));
        m4[r] = fmaxf(m4[r], __shfl_xor(m4[r], 2, 64));
        m4[r] = fmaxf(m4[r], __shfl_xor(m4[r], 4, 64));
        m4[r] = fmaxf(m4[r], __shfl_xor(m4[r], 8, 64));
    }
    if (l15 == 0) {
#pragma unroll
        for (int r = 0; r < 4; r++) redm[w][l4 * 4 + r] = m4[r];
    }
    __syncthreads();
#pragma unroll
    for (int r = 0; r < 4; r++) {
        const int row = l4 * 4 + r;
        m4[r] = fmaxf(fmaxf(redm[0][row], redm[1][row]),
                      fmaxf(redm[2][row], redm[3][row]));
        s4[r] = 0.f;
    }
#pragma unroll
    for (int ct = 0; ct < 16; ct++)
        if (ct < nt) {
#pragma unroll
            for (int r = 0; r < 4; r++) {
                float e = __expf(sc[ct][r] - m4[r]);
                sc[ct][r] = e;
                s4[r] += e;
            }
        }
#pragma unroll
    for (int r = 0; r < 4; r++) {
        s4[r] += __shfl_xor(s4[r], 1, 64);
        s4[r] += __shfl_xor(s4[r], 2, 64);
        s4[r] += __shfl_xor(s4[r], 4, 64);
        s4[r] += __shfl_xor(s4[r], 8, 64);
    }
    if (l15 == 0) {
#pragma unroll
        for (int r = 0; r < 4; r++) reds[w][l4 * 4 + r] = s4[r];
    }
    __syncthreads();
    float inv[4];
#pragma unroll
    for (int r = 0; r < 4; r++) {
        const int row = l4 * 4 + r;
        inv[r] = 1.0f / (reds[0][row] + reds[1][row] + reds[2][row] + reds[3][row]);
    }

    // ---- write probs: d_out (dtype-branched) + P_lds (bf16 for PV) --------
    const size_t obase = (size_t)probs_off + ((size_t)z * SEQ + row0) * SEQ;
#pragma unroll
    for (int ct = 0; ct < 16; ct++) {
        if (ct < nt) {
            const int col = ct * 64 + w * 16 + l15;
#pragma unroll
            for (int r = 0; r < 4; r++) {
                const int row = l4 * 4 + r;
                const float p  = sc[ct][r] * inv[r];
                const float p2 = __shfl_xor(p, 1, 64);   // col-neighbor value
                if (!(lane & 1)) {
                    const unsigned int pk =
                        ((unsigned int)bfbits(p2) << 16) | bfbits(p);
                    *(unsigned int*)&P[row][col] = pk;   // col even here
                    if (!f32)
                        *(unsigned int*)((unsigned short*)outp + obase +
                                         (size_t)row * SEQ + col) = pk;
                }
                if (f32)
                    ((float*)outp)[obase + (size_t)row * SEQ + col] = p;
            }
        }
    }
    // causal tail: exact zeros
    {
        const int c0 = nt * 64;
        if (c0 < SEQ) {
            const int rr = tid >> 4, ii = tid & 15;
            if (f32) {
                float* op = (float*)outp + obase + (size_t)rr * SEQ;
                const float4 zz = {0.f, 0.f, 0.f, 0.f};
                for (int c = c0 + ii * 4; c < SEQ; c += 64) *(float4*)(op + c) = zz;
            } else {
                unsigned short* op = (unsigned short*)outp + obase + (size_t)rr * SEQ;
                const uint4 zz = {0u, 0u, 0u, 0u};
                for (int c = c0 + ii * 8; c < SEQ; c += 128) *(uint4*)(op + c) = zz;
            }
        }
    }
    __syncthreads();   // P writes visible to all waves

    // ---- PV: no barriers, V frags from VT (global, contiguous) ------------
    f32x4 co = (f32x4){0.f, 0.f, 0.f, 0.f};
#pragma unroll
    for (int kt = 0; kt < 16; kt++) {
        if (kt < nt) {
            const bf16x8 a0 = *(const bf16x8*)&P[l15][kt * 64 + l4 * 8];
            const bf16x8 a1 = *(const bf16x8*)&P[l15][kt * 64 + 32 + l4 * 8];
            const bf16_t* vp = Vt + (size_t)(w * 16 + l15) * SEQ + kt * 64 + l4 * 8;
            const bf16x8 b0 = *(const bf16x8*)vp;
            const bf16x8 b1 = *(const bf16x8*)(vp + 32);
            co = __builtin_amdgcn_mfma_f32_16x16x32_bf16(a0, b0, co, 0, 0, 0);
            co = __builtin_amdgcn_mfma_f32_16x16x32_bf16(a1, b1, co, 0, 0, 0);
        }
    }
    bf16_t* cp = CTX + (size_t)bq * SEQ * EMB + (size_t)h * HDK
               + (size_t)row0 * EMB + w * 16 + l15;
#pragma unroll
    for (int r = 0; r < 4; r++)
        cp[(size_t)(l4 * 4 + r) * EMB] = (bf16_t)co[r];
}

static __device__ __forceinline__ float bsum(float v, float* red)
{
#pragma unroll
    for (int off = 32; off; off >>= 1) v += __shfl_down(v, off, 64);
    const int lane = threadIdx.x & 63, w = threadIdx.x >> 6;
    __syncthreads();
    if (lane == 0) red[w] = v;
    __syncthreads();
    return red[0] + red[1] + red[2] + red[3];
}

__global__ __launch_bounds__(256)
void ln_k(const float* __restrict__ proj, float* __restrict__ X,
          bf16_t* __restrict__ XB, const void* __restrict__ g, long goff,
          const void* __restrict__ bb, long boff2, const int* __restrict__ flagp)
{
    const int f32 = *flagp;
    const int row = blockIdx.x;
    const float* p = proj + (size_t)row * EMB;
    float* x  = X  + (size_t)row * EMB;
    bf16_t* xb = XB + (size_t)row * EMB;
    const int tid = threadIdx.x;
    __shared__ float red[4];

    float v[3];
    float sum = 0.f;
#pragma unroll
    for (int i = 0; i < 3; i++) { int e = tid + i * 256; v[i] = p[e] + x[e]; sum += v[i]; }
    sum = bsum(sum, red);
    const float mean = sum * (1.0f / EMB);

    float vs = 0.f;
#pragma unroll
    for (int i = 0; i < 3; i++) { float d = v[i] - mean; vs += d * d; }
    vs = bsum(vs, red);
    const float rstd = rsqrtf(vs * (1.0f / EMB) + 1e-5f);

#pragma unroll
    for (int i = 0; i < 3; i++) {
        int e = tid + i * 256;
        float y = (v[i] - mean) * rstd * loadf(g, goff + e, f32) + loadf(bb, boff2 + e, f32);
        x[e] = y;
        xb[e] = (bf16_t)y;
    }
}

__global__ __launch_bounds__(256)
void copyout_k(const float* __restrict__ X, void* __restrict__ outp,
               const int* __restrict__ flagp)
{
    const int f32 = *flagp;
    int i = blockIdx.x * 256 + threadIdx.x;
    float v = X[i];
    if (f32) ((float*)outp)[i] = v;
    else     ((bf16_t*)outp)[i] = (bf16_t)v;
}

// ---------------------------------------------------------------------------
extern "C" void kernel_launch(void* const* d_in, const int* in_sizes, int n_in,
                              void* d_out, int out_size, void* d_ws, size_t ws_size,
                              hipStream_t stream)
{
    const void* x  = d_in[0];
    const void* tp = d_in[1];
    const void* sp = d_in[2];
    const void* Wq = d_in[3];
    const void* Wk = d_in[4];
    const void* Wv = d_in[5];
    const void* Wo = d_in[6];
    const void* g1 = d_in[7];
    const void* b1 = d_in[8];
    const void* W1 = d_in[9];
    const void* W2 = d_in[10];
    const void* g2 = d_in[11];
    const void* b2 = d_in[12];

    const size_t BS   = (size_t)BATCH * SEQ;                 // 2048
    const size_t BSE  = BS * EMB;                             // 1.57M
    const size_t ATT1 = (size_t)BATCH * HEADS * SEQ * SEQ;    // 25.2M / layer

    char* ws = (char*)d_ws;
    size_t off = 0;
    auto alloc = [&](size_t bytes) { void* p = ws + off; off += (bytes + 255) & ~255ULL; return p; };

    float*  X     = (float*)alloc(BSE * 4);
    bf16_t* XB    = (bf16_t*)alloc(BSE * 2);
    bf16_t* QKV   = (bf16_t*)alloc(BS * QKVN * 2);
    bf16_t* VT    = (bf16_t*)alloc((size_t)BATCH * HEADS * HDK * SEQ * 2);
    bf16_t* CTXB  = (bf16_t*)alloc(BSE * 2);
    bf16_t* HB    = (bf16_t*)alloc(BS * DFF * 2);
    float*  PRJ   = (float*)alloc(BSE * 4);
    bf16_t* WqkvT = (bf16_t*)alloc((size_t)LYR * QKVN * EMB * 2);
    bf16_t* WoT   = (bf16_t*)alloc((size_t)LYR * EMB * EMB * 2);
    bf16_t* W1T   = (bf16_t*)alloc((size_t)LYR * DFF * EMB * 2);
    bf16_t* W2T   = (bf16_t*)alloc((size_t)LYR * EMB * DFF * 2);
    int*    pad   = (int*)alloc(BS * 4);
    int*    flag  = (int*)alloc(256);

    detect_k<<<dim3(1), 256, 0, stream>>>(Wq, flag);

    // one-time weight transposes -> bf16 [N][K]
    transp_k<<<dim3(12, 12, LYR), 256, 0, stream>>>(
        Wq, WqkvT, EMB, EMB, (long)EMB * EMB, (long)QKVN * EMB, 0, EMB, flag);
    transp_k<<<dim3(12, 12, LYR), 256, 0, stream>>>(
        Wk, WqkvT, EMB, EMB, (long)EMB * EMB, (long)QKVN * EMB, EMB, EMB, flag);
    transp_k<<<dim3(12, 12, LYR), 256, 0, stream>>>(
        Wv, WqkvT, EMB, EMB, (long)EMB * EMB, (long)QKVN * EMB, 2 * EMB, EMB, flag);
    transp_k<<<dim3(12, 12, LYR), 256, 0, stream>>>(
        Wo, WoT, EMB, EMB, (long)EMB * EMB, (long)EMB * EMB, 0, EMB, flag);
    transp_k<<<dim3(DFF / 64, 12, LYR), 256, 0, stream>>>(
        W1, W1T, EMB, DFF, (long)EMB * DFF, (long)DFF * EMB, 0, EMB, flag);
    transp_k<<<dim3(12, DFF / 64, LYR), 256, 0, stream>>>(
        W2, W2T, DFF, EMB, (long)DFF * EMB, (long)EMB * DFF, 0, DFF, flag);

    posadd_k<<<dim3((int)BS), 256, 0, stream>>>(x, tp, sp, X, XB, pad, flag);

    for (int l = 0; l < LYR; l++) {
        const long probs_off = (long)(BSE + (size_t)l * ATT1);

        // fused QKV projection: [2048,768] x [768,2304] -> bf16 QKV
        gemm128_k<0><<<dim3(16, QKVN / 128), 256, 0, stream>>>(
            XB, EMB, WqkvT + (size_t)l * QKVN * EMB, EMB, QKV, QKVN, EMB);

        // V slice -> VT [B*H][64][1024]
        vtr_k<<<dim3(SEQ / 64, BATCH * HEADS), 256, 0, stream>>>(QKV, VT);

        // fused attention: scores+mask+softmax+probs-out+PV
        attn_k<<<dim3(SEQ / 16, BATCH * HEADS), 256, 0, stream>>>(
            QKV, VT, CTXB, d_out, probs_off, pad, flag);

        // attn out projection -> fp32 PRJ, then LN1
        gemm64_k<2><<<dim3(16, EMB / 64), 256, 0, stream>>>(
            CTXB, EMB, WoT + (size_t)l * EMB * EMB, EMB, PRJ, EMB, EMB);
        ln_k<<<dim3((int)BS), 256, 0, stream>>>(PRJ, X, XB, g1, (long)l * EMB, b1, (long)l * EMB, flag);

        // FFN: relu(X W1) W2, then LN2
        gemm128_k<1><<<dim3(16, DFF / 128), 256, 0, stream>>>(
            XB, EMB, W1T + (size_t)l * DFF * EMB, EMB, HB, DFF, EMB);
        gemm64_k<2><<<dim3(16, EMB / 64), 256, 0, stream>>>(
            HB, DFF, W2T + (size_t)l * EMB * DFF, DFF, PRJ, EMB, DFF);
        ln_k<<<dim3((int)BS), 256, 0, stream>>>(PRJ, X, XB, g2, (long)l * EMB, b2, (long)l * EMB, flag);
    }

    copyout_k<<<dim3((int)(BSE / 256)), 256, 0, stream>>>(X, d_out, flag);
}

// Round 4
// 1834.465 us; speedup vs baseline: 1.9338x; 1.0413x over previous
//
#include <hip/hip_runtime.h>
#include <hip/hip_bf16.h>

#define LYR  6
#define BATCH 2
#define TOK  64
#define SEQ  1024
#define EMB  768
#define HEADS 12
#define HDK  64
#define DFF  3072
#define QKVN 2304   // 3*EMB, fused QKV output width

typedef __bf16 bf16_t;
typedef __bf16 bf16x8 __attribute__((ext_vector_type(8)));
typedef float  f32x4  __attribute__((ext_vector_type(4)));
typedef unsigned int u32;

// async global->LDS, 16B per lane; LDS dest = wave-uniform base + lane*16
#define GLDS16(g, l) __builtin_amdgcn_global_load_lds( \
    (const __attribute__((address_space(1))) u32*)(g), \
    (__attribute__((address_space(3))) u32*)(l), 16, 0, 0)

static __device__ __forceinline__ unsigned short bfbits(float f) {
    bf16_t b = (bf16_t)f; return *(unsigned short*)&b;
}
static __device__ __forceinline__ float loadf(const void* p, size_t e, int f32) {
    if (f32) return ((const float*)p)[e];
    return (float)((const bf16_t*)p)[e];
}
static __device__ __forceinline__ ushort4 load4bf(const void* p, size_t e, int f32) {
    if (f32) {
        float4 f = *(const float4*)((const float*)p + e);
        ushort4 u; u.x = bfbits(f.x); u.y = bfbits(f.y); u.z = bfbits(f.z); u.w = bfbits(f.w);
        return u;
    }
    return *(const ushort4*)((const unsigned short*)p + e);
}

// ---------------------------------------------------------------------------
// dtype detector: scan first 4096 16-bit chunks of Wq as bf16.
// ---------------------------------------------------------------------------
__global__ __launch_bounds__(256)
void detect_k(const void* w, int* flag)
{
    __shared__ int bad;
    if (threadIdx.x == 0) bad = 0;
    __syncthreads();
    const unsigned short* p = (const unsigned short*)w;
    int local = 0;
    for (int i = threadIdx.x; i < 4096; i += 256) {
        float v = (float)(*(const bf16_t*)&p[i]);
        if (!(v < 1e3f && v > -1e3f)) local = 1;   // catches NaN too
    }
    if (local) atomicOr(&bad, 1);
    __syncthreads();
    if (threadIdx.x == 0) *flag = bad;
}

// ---------------------------------------------------------------------------
// Weight transpose: src [L][K][N] (bf16 or fp32 per flag) -> dst bf16 [L][N][K]
// ---------------------------------------------------------------------------
__global__ __launch_bounds__(256)
void transp_k(const void* __restrict__ src, bf16_t* __restrict__ dst,
              int K, int N, long sstride, long dstride, long drow0, long dld,
              const int* __restrict__ flagp)
{
    __shared__ unsigned short sm[64][68];
    const int f32 = *flagp;
    const int l  = blockIdx.z;
    const int n0 = blockIdx.x * 64;
    const int k0 = blockIdx.y * 64;
    const int tid = threadIdx.x;
    const int rr = tid >> 4;       // 0..15
    const int cc = tid & 15;       // 0..15 (chunk of 4 elems)

    const size_t sb = (size_t)l * sstride;
#pragma unroll
    for (int p = 0; p < 4; p++) {
        const int kr = rr + p * 16;
        ushort4 u = load4bf(src, sb + (size_t)(k0 + kr) * N + n0 + cc * 4, f32);
        *(ushort4*)&sm[kr][cc * 4] = u;
    }
    __syncthreads();
    const size_t db = (size_t)l * dstride;
#pragma unroll
    for (int p = 0; p < 4; p++) {
        const int r2 = rr + p * 16;          // n-offset within tile
        ushort4 v;
        v.x = sm[cc * 4 + 0][r2];
        v.y = sm[cc * 4 + 1][r2];
        v.z = sm[cc * 4 + 2][r2];
        v.w = sm[cc * 4 + 3][r2];
        *(ushort4*)&dst[db + (size_t)(drow0 + n0 + r2) * dld + k0 + cc * 4] = v;
    }
}

// ---------------------------------------------------------------------------
// V transpose per layer: V slice of QKV [B*S][2304] -> VT [B*H][64][1024]
// ---------------------------------------------------------------------------
__global__ __launch_bounds__(256)
void vtr_k(const bf16_t* __restrict__ QKV, bf16_t* __restrict__ VT)
{
    __shared__ unsigned short sm[64][68];
    const int z  = blockIdx.y;            // b*H + h
    const int s0 = blockIdx.x * 64;
    const int bq = z / HEADS, h = z % HEADS;
    const int tid = threadIdx.x;
    const int rr = tid >> 4, cc = tid & 15;
    const unsigned short* src = (const unsigned short*)QKV
        + (size_t)bq * SEQ * QKVN + 2 * EMB + (size_t)h * HDK;
#pragma unroll
    for (int p = 0; p < 4; p++) {
        const int s = rr + p * 16;
        *(ushort4*)&sm[s][cc * 4] =
            *(const ushort4*)(src + (size_t)(s0 + s) * QKVN + cc * 4);
    }
    __syncthreads();
    unsigned short* dst = (unsigned short*)VT + (size_t)z * HDK * SEQ;
#pragma unroll
    for (int p = 0; p < 4; p++) {
        const int d = rr + p * 16;
        ushort4 v;
        v.x = sm[cc * 4 + 0][d];
        v.y = sm[cc * 4 + 1][d];
        v.z = sm[cc * 4 + 2][d];
        v.w = sm[cc * 4 + 3][d];
        *(ushort4*)(dst + (size_t)d * SEQ + s0 + cc * 4) = v;
    }
}

// ---------------------------------------------------------------------------
// 64x64-tile GEMM, double-buffered 2-phase: C = A[M][K] * BT[N][K]^T.
// 4 waves, wave owns 16 rows; 4 MFMA/wave/k-step; 1 barrier/k-step.
// EPI: 0 = bf16 store, 1 = bf16 relu, 2 = fp32
// ---------------------------------------------------------------------------
template<int EPI>
__global__ __launch_bounds__(256)
void gemm64_k(const bf16_t* __restrict__ A, long lda,
              const bf16_t* __restrict__ BT, long ldb,
              void* __restrict__ C, long ldc, int K)
{
    __shared__ __align__(16) unsigned short As[2][64 * 32];
    __shared__ __align__(16) unsigned short Bs[2][64 * 32];

    const int tid  = threadIdx.x;
    const int lane = tid & 63;
    const int wave = tid >> 6;
    const int bm = blockIdx.x * 64;
    const int bn = blockIdx.y * 64;
    const int srow = lane >> 2;          // row within 16-row chunk
    const int scb  = (lane & 3) * 16;    // byte col within 64B row
    const int l15 = lane & 15, l4 = lane >> 4;

    const char* gA = (const char*)A;
    const char* gB = (const char*)BT;

    f32x4 acc[4];
#pragma unroll
    for (int t = 0; t < 4; t++) acc[t] = (f32x4){0.f, 0.f, 0.f, 0.f};

    const int nst = K >> 5;

    // per-wave staging: 1 chunk (16 rows x 32 cols = 1KB) of A and of B
    auto stage = [&](int buf, int k0) {
        const char* ga = gA + ((size_t)(bm + wave * 16 + srow) * lda + k0) * 2 + scb;
        GLDS16(ga, &As[buf][wave * 16 * 32]);
        const char* gb = gB + ((size_t)(bn + wave * 16 + srow) * ldb + k0) * 2 + scb;
        GLDS16(gb, &Bs[buf][wave * 16 * 32]);
    };

    stage(0, 0);
    __syncthreads();

    int cur = 0;
    for (int t = 0; t < nst; t++) {
        if (t + 1 < nst) stage(cur ^ 1, (t + 1) << 5);

        const bf16x8 av = *(const bf16x8*)&As[cur][(wave * 16 + l15) * 32 + l4 * 8];
#pragma unroll
        for (int bf = 0; bf < 4; bf++) {
            const bf16x8 bv = *(const bf16x8*)&Bs[cur][(bf * 16 + l15) * 32 + l4 * 8];
            acc[bf] = __builtin_amdgcn_mfma_f32_16x16x32_bf16(av, bv, acc[bf], 0, 0, 0);
        }
        __syncthreads();   // drains stage vmcnt + lds reads, then barrier
        cur ^= 1;
    }

#pragma unroll
    for (int bf = 0; bf < 4; bf++) {
#pragma unroll
        for (int r = 0; r < 4; r++) {
            const int row = bm + wave * 16 + l4 * 4 + r;
            const int col = bn + bf * 16 + l15;
            const float v = acc[bf][r];
            const size_t idx = (size_t)row * ldc + col;
            if constexpr (EPI == 0) {
                ((bf16_t*)C)[idx] = (bf16_t)v;
            } else if constexpr (EPI == 1) {
                ((bf16_t*)C)[idx] = (bf16_t)(v > 0.f ? v : 0.f);
            } else {
                ((float*)C)[idx] = v;
            }
        }
    }
}

// ---------------------------------------------------------------------------
// 128x128-tile GEMM, double-buffered 2-phase: 16 MFMA/wave/k-step,
// 32KB LDS, 1 barrier/k-step.
// ---------------------------------------------------------------------------
template<int EPI>
__global__ __launch_bounds__(256)
void gemm128_k(const bf16_t* __restrict__ A, long lda,
               const bf16_t* __restrict__ BT, long ldb,
               void* __restrict__ C, long ldc, int K)
{
    __shared__ __align__(16) unsigned short As[2][128 * 32];
    __shared__ __align__(16) unsigned short Bs[2][128 * 32];

    const int tid  = threadIdx.x;
    const int lane = tid & 63;
    const int wave = tid >> 6;
    const int bm = blockIdx.x * 128;
    const int bn = blockIdx.y * 128;
    const int srow = lane >> 2;
    const int scb  = (lane & 3) * 16;
    const int l15 = lane & 15, l4 = lane >> 4;
    const int wr = wave >> 1, wc = wave & 1;

    const char* gA = (const char*)A;
    const char* gB = (const char*)BT;

    f32x4 acc[4][4];
#pragma unroll
    for (int m = 0; m < 4; m++)
#pragma unroll
        for (int n = 0; n < 4; n++) acc[m][n] = (f32x4){0.f, 0.f, 0.f, 0.f};

    const int nst = K >> 5;

    auto stage = [&](int buf, int k0) {
#pragma unroll
        for (int j = 0; j < 2; j++) {
            const int rb = (j * 4 + wave) * 16;
            const char* ga = gA + ((size_t)(bm + rb + srow) * lda + k0) * 2 + scb;
            GLDS16(ga, &As[buf][rb * 32]);
        }
#pragma unroll
        for (int j = 0; j < 2; j++) {
            const int rb = (j * 4 + wave) * 16;
            const char* gb = gB + ((size_t)(bn + rb + srow) * ldb + k0) * 2 + scb;
            GLDS16(gb, &Bs[buf][rb * 32]);
        }
    };

    stage(0, 0);
    __syncthreads();

    int cur = 0;
    for (int t = 0; t < nst; t++) {
        if (t + 1 < nst) stage(cur ^ 1, (t + 1) << 5);

        bf16x8 a[4], b[4];
#pragma unroll
        for (int m = 0; m < 4; m++)
            a[m] = *(const bf16x8*)&As[cur][(wr * 64 + m * 16 + l15) * 32 + l4 * 8];
#pragma unroll
        for (int n = 0; n < 4; n++)
            b[n] = *(const bf16x8*)&Bs[cur][(wc * 64 + n * 16 + l15) * 32 + l4 * 8];
#pragma unroll
        for (int m = 0; m < 4; m++)
#pragma unroll
            for (int n = 0; n < 4; n++)
                acc[m][n] = __builtin_amdgcn_mfma_f32_16x16x32_bf16(a[m], b[n], acc[m][n], 0, 0, 0);
        __syncthreads();
        cur ^= 1;
    }

#pragma unroll
    for (int m = 0; m < 4; m++) {
#pragma unroll
        for (int n = 0; n < 4; n++) {
#pragma unroll
            for (int r = 0; r < 4; r++) {
                const int row = bm + wr * 64 + m * 16 + l4 * 4 + r;
                const int col = bn + wc * 64 + n * 16 + l15;
                const float v = acc[m][n][r];
                const size_t idx = (size_t)row * ldc + col;
                if constexpr (EPI == 0) {
                    ((bf16_t*)C)[idx] = (bf16_t)v;
                } else if constexpr (EPI == 1) {
                    ((bf16_t*)C)[idx] = (bf16_t)(v > 0.f ? v : 0.f);
                } else {
                    ((float*)C)[idx] = v;
                }
            }
        }
    }
}

__global__ __launch_bounds__(256)
void posadd_k(const void* __restrict__ x, const void* __restrict__ tp,
              const void* __restrict__ sp, float* __restrict__ X,
              bf16_t* __restrict__ XB, int* __restrict__ pad,
              const int* __restrict__ flagp)
{
    const int f32 = *flagp;
    const int row = blockIdx.x;              // b*S + s
    const int s = row % SEQ;
    const int f = s / TOK, tt = s % TOK;
    const int tid = threadIdx.x;
#pragma unroll
    for (int i = 0; i < 3; i++) {
        int e = tid + i * 256;
        float v = loadf(x, (size_t)row * EMB + e, f32)
                + loadf(tp, (size_t)f * EMB + e, f32)
                + loadf(sp, (size_t)tt * EMB + e, f32);
        X[(size_t)row * EMB + e]  = v;
        XB[(size_t)row * EMB + e] = (bf16_t)v;
        if (e == 0) pad[row] = (v == 0.0f) ? 1 : 0;
    }
}

// ---------------------------------------------------------------------------
// Fused attention: K frags direct from global (L2), V frags from VT.
// 3 __syncthreads per block.
// ---------------------------------------------------------------------------
__global__ __launch_bounds__(256)
void attn_k(const bf16_t* __restrict__ QKV, const bf16_t* __restrict__ VT,
            bf16_t* __restrict__ CTX, void* __restrict__ outp, long probs_off,
            const int* __restrict__ pad, const int* __restrict__ flagp)
{
    __shared__ __align__(16) unsigned short P[16][1032];  // probs bf16 [row][col]
    __shared__ float redm[4][16];
    __shared__ float reds[4][16];

    const int f32 = *flagp;
    const int bx  = blockIdx.x;              // query tile (16 rows)
    const int z   = blockIdx.y;              // b*H + h
    const int bq  = z / HEADS, h = z % HEADS;
    const int tid = threadIdx.x;
    const int lane = tid & 63;
    const int w    = tid >> 6;
    const int l15  = lane & 15;
    const int l4   = lane >> 4;

    const size_t qoff = (size_t)bq * SEQ * QKVN + (size_t)h * HDK;
    const bf16_t* Qp = QKV + qoff;
    const bf16_t* Kp = QKV + qoff + EMB;
    const bf16_t* Vt = VT + (size_t)z * HDK * SEQ;
    const int row0 = bx * 16;
    const int nt   = (bx >> 2) + 1;          // causal col-tile count (of 16)

    bf16x8 aq0, aq1;
    {
        const bf16_t* qp = Qp + (size_t)(row0 + l15) * QKVN + l4 * 8;
        aq0 = *(const bf16x8*)qp;
        aq1 = *(const bf16x8*)(qp + 32);
    }

    f32x4 sc[16];   // scores: wave w owns cols ct*64 + w*16 + l15, rows l4*4+r

    // ---- QK^T: no barriers, K frags straight from L2 ----------------------
#pragma unroll
    for (int ct = 0; ct < 16; ct++) {
        if (ct < nt) {
            const bf16_t* kp = Kp + (size_t)(ct * 64 + w * 16 + l15) * QKVN + l4 * 8;
            const bf16x8 b0 = *(const bf16x8*)kp;
            const bf16x8 b1 = *(const bf16x8*)(kp + 32);
            f32x4 a = (f32x4){0.f, 0.f, 0.f, 0.f};
            a = __builtin_amdgcn_mfma_f32_16x16x32_bf16(aq0, b0, a, 0, 0, 0);
            a = __builtin_amdgcn_mfma_f32_16x16x32_bf16(aq1, b1, a, 0, 0, 0);
            const int col = ct * 64 + w * 16 + l15;
            const int pd  = pad[bq * SEQ + col];
#pragma unroll
            for (int r = 0; r < 4; r++) {
                float v = a[r] * 0.125f;
                if (col > row0 + l4 * 4 + r || pd) v = -1e9f;
                sc[ct][r] = v;
            }
        }
    }

    // ---- softmax ----------------------------------------------------------
    float m4[4], s4[4];
#pragma unroll
    for (int r = 0; r < 4; r++) m4[r] = -3.0e38f;
#pragma unroll
    for (int ct = 0; ct < 16; ct++)
        if (ct < nt) {
#pragma unroll
            for (int r = 0; r < 4; r++) m4[r] = fmaxf(m4[r], sc[ct][r]);
        }
#pragma unroll
    for (int r = 0; r < 4; r++) {
        m4[r] = fmaxf(m4[r], __shfl_xor(m4[r], 1, 64));
        m4[r] = fmaxf(m4[r], __shfl_xor(m4[r], 2, 64));
        m4[r] = fmaxf(m4[r], __shfl_xor(m4[r], 4, 64));
        m4[r] = fmaxf(m4[r], __shfl_xor(m4[r], 8, 64));
    }
    if (l15 == 0) {
#pragma unroll
        for (int r = 0; r < 4; r++) redm[w][l4 * 4 + r] = m4[r];
    }
    __syncthreads();
#pragma unroll
    for (int r = 0; r < 4; r++) {
        const int row = l4 * 4 + r;
        m4[r] = fmaxf(fmaxf(redm[0][row], redm[1][row]),
                      fmaxf(redm[2][row], redm[3][row]));
        s4[r] = 0.f;
    }
#pragma unroll
    for (int ct = 0; ct < 16; ct++)
        if (ct < nt) {
#pragma unroll
            for (int r = 0; r < 4; r++) {
                float e = __expf(sc[ct][r] - m4[r]);
                sc[ct][r] = e;
                s4[r] += e;
            }
        }
#pragma unroll
    for (int r = 0; r < 4; r++) {
        s4[r] += __shfl_xor(s4[r], 1, 64);
        s4[r] += __shfl_xor(s4[r], 2, 64);
        s4[r] += __shfl_xor(s4[r], 4, 64);
        s4[r] += __shfl_xor(s4[r], 8, 64);
    }
    if (l15 == 0) {
#pragma unroll
        for (int r = 0; r < 4; r++) reds[w][l4 * 4 + r] = s4[r];
    }
    __syncthreads();
    float inv[4];
#pragma unroll
    for (int r = 0; r < 4; r++) {
        const int row = l4 * 4 + r;
        inv[r] = 1.0f / (reds[0][row] + reds[1][row] + reds[2][row] + reds[3][row]);
    }

    // ---- write probs: d_out (dtype-branched) + P_lds (bf16 for PV) --------
    const size_t obase = (size_t)probs_off + ((size_t)z * SEQ + row0) * SEQ;
#pragma unroll
    for (int ct = 0; ct < 16; ct++) {
        if (ct < nt) {
            const int col = ct * 64 + w * 16 + l15;
#pragma unroll
            for (int r = 0; r < 4; r++) {
                const int row = l4 * 4 + r;
                const float p  = sc[ct][r] * inv[r];
                const float p2 = __shfl_xor(p, 1, 64);   // col-neighbor value
                if (!(lane & 1)) {
                    const unsigned int pk =
                        ((unsigned int)bfbits(p2) << 16) | bfbits(p);
                    *(unsigned int*)&P[row][col] = pk;   // col even here
                    if (!f32)
                        *(unsigned int*)((unsigned short*)outp + obase +
                                         (size_t)row * SEQ + col) = pk;
                }
                if (f32)
                    ((float*)outp)[obase + (size_t)row * SEQ + col] = p;
            }
        }
    }
    // causal tail: exact zeros
    {
        const int c0 = nt * 64;
        if (c0 < SEQ) {
            const int rr = tid >> 4, ii = tid & 15;
            if (f32) {
                float* op = (float*)outp + obase + (size_t)rr * SEQ;
                const float4 zz = {0.f, 0.f, 0.f, 0.f};
                for (int c = c0 + ii * 4; c < SEQ; c += 64) *(float4*)(op + c) = zz;
            } else {
                unsigned short* op = (unsigned short*)outp + obase + (size_t)rr * SEQ;
                const uint4 zz = {0u, 0u, 0u, 0u};
                for (int c = c0 + ii * 8; c < SEQ; c += 128) *(uint4*)(op + c) = zz;
            }
        }
    }
    __syncthreads();   // P writes visible to all waves

    // ---- PV: no barriers, V frags from VT (global, contiguous) ------------
    f32x4 co = (f32x4){0.f, 0.f, 0.f, 0.f};
#pragma unroll
    for (int kt = 0; kt < 16; kt++) {
        if (kt < nt) {
            const bf16x8 a0 = *(const bf16x8*)&P[l15][kt * 64 + l4 * 8];
            const bf16x8 a1 = *(const bf16x8*)&P[l15][kt * 64 + 32 + l4 * 8];
            const bf16_t* vp = Vt + (size_t)(w * 16 + l15) * SEQ + kt * 64 + l4 * 8;
            const bf16x8 b0 = *(const bf16x8*)vp;
            const bf16x8 b1 = *(const bf16x8*)(vp + 32);
            co = __builtin_amdgcn_mfma_f32_16x16x32_bf16(a0, b0, co, 0, 0, 0);
            co = __builtin_amdgcn_mfma_f32_16x16x32_bf16(a1, b1, co, 0, 0, 0);
        }
    }
    bf16_t* cp = CTX + (size_t)bq * SEQ * EMB + (size_t)h * HDK
               + (size_t)row0 * EMB + w * 16 + l15;
#pragma unroll
    for (int r = 0; r < 4; r++)
        cp[(size_t)(l4 * 4 + r) * EMB] = (bf16_t)co[r];
}

static __device__ __forceinline__ float bsum(float v, float* red)
{
#pragma unroll
    for (int off = 32; off; off >>= 1) v += __shfl_down(v, off, 64);
    const int lane = threadIdx.x & 63, w = threadIdx.x >> 6;
    __syncthreads();
    if (lane == 0) red[w] = v;
    __syncthreads();
    return red[0] + red[1] + red[2] + red[3];
}

__global__ __launch_bounds__(256)
void ln_k(const float* __restrict__ proj, float* __restrict__ X,
          bf16_t* __restrict__ XB, const void* __restrict__ g, long goff,
          const void* __restrict__ bb, long boff2, const int* __restrict__ flagp)
{
    const int f32 = *flagp;
    const int row = blockIdx.x;
    const float* p = proj + (size_t)row * EMB;
    float* x  = X  + (size_t)row * EMB;
    bf16_t* xb = XB + (size_t)row * EMB;
    const int tid = threadIdx.x;
    __shared__ float red[4];

    float v[3];
    float sum = 0.f;
#pragma unroll
    for (int i = 0; i < 3; i++) { int e = tid + i * 256; v[i] = p[e] + x[e]; sum += v[i]; }
    sum = bsum(sum, red);
    const float mean = sum * (1.0f / EMB);

    float vs = 0.f;
#pragma unroll
    for (int i = 0; i < 3; i++) { float d = v[i] - mean; vs += d * d; }
    vs = bsum(vs, red);
    const float rstd = rsqrtf(vs * (1.0f / EMB) + 1e-5f);

#pragma unroll
    for (int i = 0; i < 3; i++) {
        int e = tid + i * 256;
        float y = (v[i] - mean) * rstd * loadf(g, goff + e, f32) + loadf(bb, boff2 + e, f32);
        x[e] = y;
        xb[e] = (bf16_t)y;
    }
}

__global__ __launch_bounds__(256)
void copyout_k(const float* __restrict__ X, void* __restrict__ outp,
               const int* __restrict__ flagp)
{
    const int f32 = *flagp;
    int i = blockIdx.x * 256 + threadIdx.x;
    float v = X[i];
    if (f32) ((float*)outp)[i] = v;
    else     ((bf16_t*)outp)[i] = (bf16_t)v;
}

// ---------------------------------------------------------------------------
extern "C" void kernel_launch(void* const* d_in, const int* in_sizes, int n_in,
                              void* d_out, int out_size, void* d_ws, size_t ws_size,
                              hipStream_t stream)
{
    const void* x  = d_in[0];
    const void* tp = d_in[1];
    const void* sp = d_in[2];
    const void* Wq = d_in[3];
    const void* Wk = d_in[4];
    const void* Wv = d_in[5];
    const void* Wo = d_in[6];
    const void* g1 = d_in[7];
    const void* b1 = d_in[8];
    const void* W1 = d_in[9];
    const void* W2 = d_in[10];
    const void* g2 = d_in[11];
    const void* b2 = d_in[12];

    const size_t BS   = (size_t)BATCH * SEQ;                 // 2048
    const size_t BSE  = BS * EMB;                             // 1.57M
    const size_t ATT1 = (size_t)BATCH * HEADS * SEQ * SEQ;    // 25.2M / layer

    char* ws = (char*)d_ws;
    size_t off = 0;
    auto alloc = [&](size_t bytes) { void* p = ws + off; off += (bytes + 255) & ~255ULL; return p; };

    float*  X     = (float*)alloc(BSE * 4);
    bf16_t* XB    = (bf16_t*)alloc(BSE * 2);
    bf16_t* QKV   = (bf16_t*)alloc(BS * QKVN * 2);
    bf16_t* VT    = (bf16_t*)alloc((size_t)BATCH * HEADS * HDK * SEQ * 2);
    bf16_t* CTXB  = (bf16_t*)alloc(BSE * 2);
    bf16_t* HB    = (bf16_t*)alloc(BS * DFF * 2);
    float*  PRJ   = (float*)alloc(BSE * 4);
    bf16_t* WqkvT = (bf16_t*)alloc((size_t)LYR * QKVN * EMB * 2);
    bf16_t* WoT   = (bf16_t*)alloc((size_t)LYR * EMB * EMB * 2);
    bf16_t* W1T   = (bf16_t*)alloc((size_t)LYR * DFF * EMB * 2);
    bf16_t* W2T   = (bf16_t*)alloc((size_t)LYR * EMB * DFF * 2);
    int*    pad   = (int*)alloc(BS * 4);
    int*    flag  = (int*)alloc(256);

    detect_k<<<dim3(1), 256, 0, stream>>>(Wq, flag);

    // one-time weight transposes -> bf16 [N][K]
    transp_k<<<dim3(12, 12, LYR), 256, 0, stream>>>(
        Wq, WqkvT, EMB, EMB, (long)EMB * EMB, (long)QKVN * EMB, 0, EMB, flag);
    transp_k<<<dim3(12, 12, LYR), 256, 0, stream>>>(
        Wk, WqkvT, EMB, EMB, (long)EMB * EMB, (long)QKVN * EMB, EMB, EMB, flag);
    transp_k<<<dim3(12, 12, LYR), 256, 0, stream>>>(
        Wv, WqkvT, EMB, EMB, (long)EMB * EMB, (long)QKVN * EMB, 2 * EMB, EMB, flag);
    transp_k<<<dim3(12, 12, LYR), 256, 0, stream>>>(
        Wo, WoT, EMB, EMB, (long)EMB * EMB, (long)EMB * EMB, 0, EMB, flag);
    transp_k<<<dim3(DFF / 64, 12, LYR), 256, 0, stream>>>(
        W1, W1T, EMB, DFF, (long)EMB * DFF, (long)DFF * EMB, 0, EMB, flag);
    transp_k<<<dim3(12, DFF / 64, LYR), 256, 0, stream>>>(
        W2, W2T, DFF, EMB, (long)DFF * EMB, (long)EMB * DFF, 0, DFF, flag);

    posadd_k<<<dim3((int)BS), 256, 0, stream>>>(x, tp, sp, X, XB, pad, flag);

    for (int l = 0; l < LYR; l++) {
        const long probs_off = (long)(BSE + (size_t)l * ATT1);

        // fused QKV projection: [2048,768] x [768,2304] -> bf16 QKV
        gemm128_k<0><<<dim3(16, QKVN / 128), 256, 0, stream>>>(
            XB, EMB, WqkvT + (size_t)l * QKVN * EMB, EMB, QKV, QKVN, EMB);

        // V slice -> VT [B*H][64][1024]
        vtr_k<<<dim3(SEQ / 64, BATCH * HEADS), 256, 0, stream>>>(QKV, VT);

        // fused attention: scores+mask+softmax+probs-out+PV
        attn_k<<<dim3(SEQ / 16, BATCH * HEADS), 256, 0, stream>>>(
            QKV, VT, CTXB, d_out, probs_off, pad, flag);

        // attn out projection -> fp32 PRJ, then LN1
        gemm64_k<2><<<dim3(32, EMB / 64), 256, 0, stream>>>(
            CTXB, EMB, WoT + (size_t)l * EMB * EMB, EMB, PRJ, EMB, EMB);
        ln_k<<<dim3((int)BS), 256, 0, stream>>>(PRJ, X, XB, g1, (long)l * EMB, b1, (long)l * EMB, flag);

        // FFN: relu(X W1) W2, then LN2
        gemm128_k<1><<<dim3(16, DFF / 128), 256, 0, stream>>>(
            XB, EMB, W1T + (size_t)l * DFF * EMB, EMB, HB, DFF, EMB);
        gemm64_k<2><<<dim3(32, EMB / 64), 256, 0, stream>>>(
            HB, DFF, W2T + (size_t)l * EMB * DFF, DFF, PRJ, EMB, DFF);
        ln_k<<<dim3((int)BS), 256, 0, stream>>>(PRJ, X, XB, g2, (long)l * EMB, b2, (long)l * EMB, flag);
    }

    copyout_k<<<dim3((int)(BSE / 256)), 256, 0, stream>>>(X, d_out, flag);
}